// Round 6
// baseline (676.434 us; speedup 1.0000x reference)
//
#include <hip/hip_runtime.h>
#include <hip/hip_fp16.h>
#include <math.h>

#define NEG_SLOPE 0.2f
typedef unsigned int u32;
typedef unsigned short u16;

__device__ __forceinline__ u32 pack_h2(float a, float b) {
    __half2 h = __floats2half2_rn(a, b);
    return *(u32*)&h;
}
__device__ __forceinline__ float2 unpack_h2(u32 v) {
    return __half22float2(*(const __half2*)&v);
}

// ---- tiny one-time transpose: src [R][C] -> dst [C][R] ----
__global__ void transpose_kernel(const float* __restrict__ src, float* __restrict__ dst,
                                 int R, int C) {
    int idx = blockIdx.x * blockDim.x + threadIdx.x;
    if (idx >= R * C) return;
    int k = idx % C, n = idx / C;
    dst[(size_t)k * R + n] = src[(size_t)n * C + k];
}

// ---- Register-blocked tiled GEMM: H(fp16)[n][o] = dot(act(A[n][:]), WT[:][o]) ----
template <int K, int OUT, int TN, bool ELU>
__global__ __launch_bounds__(256) void gemm_fused(
        const float* __restrict__ A, const float* __restrict__ WT,
        const float* __restrict__ asrc, const float* __restrict__ adst,
        u16* __restrict__ H, float* __restrict__ s_out, float* __restrict__ d_out_,
        int N) {
    constexpr int BM = 128, BK = 32, TM = 8;
    constexpr int BMP = BM + 4;
    const int t = threadIdx.x;
    const int tr = t >> 4, tc = t & 15;
    const int n0 = blockIdx.x * BM;
    const int nrow = min(BM, N - n0);

    __shared__ float As[BK][BMP];
    __shared__ float Bs[BK][OUT];

    float acc[TM][TN];
#pragma unroll
    for (int i = 0; i < TM; ++i)
#pragma unroll
        for (int j = 0; j < TN; ++j) acc[i][j] = 0.f;

    for (int k0 = 0; k0 < K; k0 += BK) {
#pragma unroll
        for (int it = 0; it < (BM * BK / 4) / 256; ++it) {
            int q = t + 256 * it;
            int m = q >> 3;
            int kq = q & 7;
            float4 v = make_float4(0.f, 0.f, 0.f, 0.f);
            if (m < nrow) v = *(const float4*)&A[(size_t)(n0 + m) * K + k0 + 4 * kq];
            if (ELU) {
                v.x = v.x > 0.f ? v.x : expm1f(v.x);
                v.y = v.y > 0.f ? v.y : expm1f(v.y);
                v.z = v.z > 0.f ? v.z : expm1f(v.z);
                v.w = v.w > 0.f ? v.w : expm1f(v.w);
            }
            As[4 * kq + 0][m] = v.x;
            As[4 * kq + 1][m] = v.y;
            As[4 * kq + 2][m] = v.z;
            As[4 * kq + 3][m] = v.w;
        }
#pragma unroll
        for (int it = 0; it < (BK * OUT / 4) / 256; ++it) {
            int q = t + 256 * it;
            int kk = q / (OUT / 4);
            int j = q % (OUT / 4);
            *(float4*)&Bs[kk][4 * j] = *(const float4*)&WT[(size_t)(k0 + kk) * OUT + 4 * j];
        }
        __syncthreads();

        for (int k = 0; k < BK; ++k) {
            float a[TM], b[TN];
            *(float4*)&a[0] = *(const float4*)&As[k][TM * tr];
            *(float4*)&a[4] = *(const float4*)&As[k][TM * tr + 4];
#pragma unroll
            for (int j4 = 0; j4 < TN / 4; ++j4)
                *(float4*)&b[4 * j4] = *(const float4*)&Bs[k][TN * tc + 4 * j4];
#pragma unroll
            for (int i = 0; i < TM; ++i)
#pragma unroll
                for (int j = 0; j < TN; ++j) acc[i][j] = fmaf(a[i], b[j], acc[i][j]);
        }
        __syncthreads();
    }

    // epilogue: fp16 H rows + fused score dots (f32 accs)
#pragma unroll
    for (int i = 0; i < TM; ++i) {
        int m = TM * tr + i;
        if (m < nrow) {
            u32 pk[TN / 2];
#pragma unroll
            for (int j2 = 0; j2 < TN / 2; ++j2)
                pk[j2] = pack_h2(acc[i][2 * j2], acc[i][2 * j2 + 1]);
            if (TN == 8)
                *(uint4*)&H[(size_t)(n0 + m) * OUT + TN * tc] = *(uint4*)pk;
            else
                *(uint2*)&H[(size_t)(n0 + m) * OUT + TN * tc] = *(uint2*)pk;
        }
    }
#pragma unroll
    for (int i = 0; i < TM; ++i) {
        float vs = 0.f, vd = 0.f;
#pragma unroll
        for (int j = 0; j < TN; ++j) {
            vs = fmaf(acc[i][j], asrc[TN * tc + j], vs);
            vd = fmaf(acc[i][j], adst[TN * tc + j], vd);
        }
#pragma unroll
        for (int off = 8; off >= 1; off >>= 1) {
            vs += __shfl_down(vs, off, 16);
            vd += __shfl_down(vd, off, 16);
        }
        int m = TM * tr + i;
        if (tc == 0 && m < nrow) {
            s_out[n0 + m] = vs;
            d_out_[n0 + m] = vd;
        }
    }
}

// ---- CSR build: histogram -> scan -> scatter (round-3 verified versions) ----
__global__ void hist_kernel(const int* __restrict__ row, int* __restrict__ cnt, int E) {
    int i = blockIdx.x * blockDim.x + threadIdx.x;
    if (i < E) atomicAdd(&cnt[row[i]], 1);
}

__global__ __launch_bounds__(1024) void scan1_kernel(const int* __restrict__ cnt,
                                                     int* __restrict__ exc,
                                                     int* __restrict__ bsum, int N) {
    __shared__ int s[1024];
    const int t = threadIdx.x;
    const int i = blockIdx.x * 1024 + t;
    int v = (i < N) ? cnt[i] : 0;
    s[t] = v;
    __syncthreads();
    for (int off = 1; off < 1024; off <<= 1) {
        int x = (t >= off) ? s[t - off] : 0;
        __syncthreads();
        s[t] += x;
        __syncthreads();
    }
    if (i < N) exc[i] = s[t] - v;
    if (t == 1023) bsum[blockIdx.x] = s[t];
}

__global__ void scan2_kernel(int* __restrict__ bsum, int* __restrict__ boff, int nb) {
    if (threadIdx.x == 0 && blockIdx.x == 0) {
        int acc = 0;
        for (int i = 0; i < nb; ++i) { boff[i] = acc; acc += bsum[i]; }
    }
}

__global__ void scan3_kernel(int* __restrict__ rp, const int* __restrict__ boff,
                             int N, int E) {
    int i = blockIdx.x * blockDim.x + threadIdx.x;
    if (i < N) rp[i] += boff[i >> 10];
    if (i == 0) rp[N] = E;
}

__global__ void scatter_kernel(const int* __restrict__ row, const int* __restrict__ col,
                               const int* __restrict__ rp, int* __restrict__ off,
                               int* __restrict__ cs, int E) {
    int i = blockIdx.x * blockDim.x + threadIdx.x;
    if (i >= E) return;
    int r = row[i];
    int p = rp[r] + atomicAdd(&off[r], 1);
    cs[p] = col[i];
}

// ---- Fused GAT layer over CSR (round-3 control flow), fp16 feature gather ----
template <int D>
__global__ __launch_bounds__(256) void gat_csr_f16(
        const int* __restrict__ rp, const int* __restrict__ cs,
        const float* __restrict__ s, const float* __restrict__ d,
        const u32* __restrict__ fp,  // packed fp16 pairs, row stride D/2
        float* __restrict__ out, int N) {
    const int wid = threadIdx.x >> 6;
    const int lane = threadIdx.x & 63;
    const int r = blockIdx.x * 4 + wid;
    if (r >= N) return;
    const int start = rp[r], end = rp[r + 1];
    const float sr = s[r];

    // phase 1: wave-parallel max over edges
    float m = -INFINITY;
    for (int j = start + lane; j < end; j += 64) {
        float e = sr + d[cs[j]];
        e = (e >= 0.f) ? e : NEG_SLOPE * e;
        m = fmaxf(m, e);
    }
#pragma unroll
    for (int off = 32; off >= 1; off >>= 1) m = fmaxf(m, __shfl_xor(m, off));

    // phase 2: wave-parallel denom
    float den = 0.f;
    for (int j = start + lane; j < end; j += 64) {
        float e = sr + d[cs[j]];
        e = (e >= 0.f) ? e : NEG_SLOPE * e;
        den += __expf(e - m);
    }
#pragma unroll
    for (int off = 32; off >= 1; off >>= 1) den += __shfl_xor(den, off);
    const float inv = (end > start) ? 1.f / den : 0.f;

    // phase 3: serial edge loop, lanes parallel over D dims
    float acc0 = 0.f, acc1 = 0.f;
    for (int j = start; j < end; ++j) {
        int c = __builtin_amdgcn_readfirstlane(cs[j]);  // wave-uniform
        float e = sr + d[c];
        e = (e >= 0.f) ? e : NEG_SLOPE * e;
        float alpha = __expf(e - m) * inv;
        if (D == 128) {
            float2 v = unpack_h2(fp[(size_t)c * 64 + lane]);
            acc0 = fmaf(alpha, v.x, acc0);
            acc1 = fmaf(alpha, v.y, acc1);
        } else {
            float2 v = unpack_h2(fp[(size_t)c * 32 + (lane >> 1)]);
            acc0 = fmaf(alpha, (lane & 1) ? v.y : v.x, acc0);
        }
    }
    if (D == 128)
        *(float2*)&out[(size_t)r * D + 2 * lane] = make_float2(acc0, acc1);
    else
        out[(size_t)r * D + lane] = acc0;
}

extern "C" void kernel_launch(void* const* d_in, const int* in_sizes, int n_in,
                              void* d_out, int out_size, void* d_ws, size_t ws_size,
                              hipStream_t stream) {
    const float* x   = (const float*)d_in[0];
    const int*   edg = (const int*)d_in[1];
    const float* W1  = (const float*)d_in[2];
    const float* W2  = (const float*)d_in[3];
    const float* as1 = (const float*)d_in[4];
    const float* ad1 = (const float*)d_in[5];
    const float* as2 = (const float*)d_in[6];
    const float* ad2 = (const float*)d_in[7];

    const int N = in_sizes[0] / 256;
    const int E = in_sizes[1] / 2;
    const int* row = edg;
    const int* col = edg + E;

    // Workspace layout
    char* p = (char*)d_ws;
    u16* h1f = (u16*)p;     p += (size_t)N * 128 * 2;   // layer-1 features, fp16
    u16* h2f = (u16*)p;     p += (size_t)N * 64 * 2;    // layer-2 features, fp16
    float* g1 = (float*)p;  p += (size_t)N * 128 * 4;   // GAT1 output, f32
    float* sm = (float*)p;  p += (size_t)N * 4 * 4;     // s1,d1,s2,d2
    float* s1 = sm + (size_t)N * 0;
    float* d1 = sm + (size_t)N * 1;
    float* s2 = sm + (size_t)N * 2;
    float* d2 = sm + (size_t)N * 3;
    float* W1T = (float*)p; p += (size_t)256 * 128 * 4;
    float* W2T = (float*)p; p += (size_t)128 * 64 * 4;
    int* cnt = (int*)p;     p += (size_t)N * 4;
    int* off = (int*)p;     p += (size_t)N * 4;
    int* rp  = (int*)p;     p += (size_t)(N + 1) * 4;
    int* bsum = (int*)p;    p += 1024 * 4;
    int* boff = (int*)p;    p += 1024 * 4;
    int* cs  = (int*)p;     p += (size_t)E * 4;

    // Round-3 memset set (parity with known-good config)
    hipMemsetAsync(g1, 0, (size_t)N * 128 * 4, stream);
    hipMemsetAsync(sm, 0, (size_t)N * 4 * 4, stream);
    hipMemsetAsync(cnt, 0, (size_t)N * 2 * 4, stream);  // cnt + off
    hipMemsetAsync(d_out, 0, (size_t)out_size * 4, stream);

    transpose_kernel<<<(128 * 256 + 255) / 256, 256, 0, stream>>>(W1, W1T, 128, 256);
    transpose_kernel<<<(64 * 128 + 255) / 256, 256, 0, stream>>>(W2, W2T, 64, 128);

    const int EB = (E + 255) / 256;
    const int GB = (N + 127) / 128;
    const int SB = (N + 1023) / 1024;

    // CSR build (row shared by both layers)
    hist_kernel<<<EB, 256, 0, stream>>>(row, cnt, E);
    scan1_kernel<<<SB, 1024, 0, stream>>>(cnt, rp, bsum, N);
    scan2_kernel<<<1, 64, 0, stream>>>(bsum, boff, SB);
    scan3_kernel<<<(N + 256) / 256, 256, 0, stream>>>(rp, boff, N, E);
    scatter_kernel<<<EB, 256, 0, stream>>>(row, col, rp, off, cs, E);

    // Layer 1
    gemm_fused<256, 128, 8, false><<<GB, 256, 0, stream>>>(x, W1T, as1, ad1, h1f, s1, d1, N);
    gat_csr_f16<128><<<(N + 3) / 4, 256, 0, stream>>>(rp, cs, s1, d1, (const u32*)h1f, g1, N);

    // Layer 2 (ELU fused into GEMM2 A-staging)
    gemm_fused<128, 64, 4, true><<<GB, 256, 0, stream>>>(g1, W2T, as2, ad2, h2f, s2, d2, N);
    gat_csr_f16<64><<<(N + 3) / 4, 256, 0, stream>>>(rp, cs, s2, d2, (const u32*)h2f,
                                                     (float*)d_out, N);
}

// Round 7
// 450.685 us; speedup vs baseline: 1.5009x; 1.5009x over previous
//
#include <hip/hip_runtime.h>
#include <hip/hip_fp16.h>
#include <math.h>

#define NEG_SLOPE 0.2f
typedef unsigned int u32;
typedef unsigned short u16;

__device__ __forceinline__ u32 pack_h2(float a, float b) {
    __half2 h = __floats2half2_rn(a, b);
    return *(u32*)&h;
}
__device__ __forceinline__ float2 unpack_h2(u32 v) {
    return __half22float2(*(const __half2*)&v);
}

// ---- tiny one-time transpose: src [R][C] -> dst [C][R] ----
__global__ void transpose_kernel(const float* __restrict__ src, float* __restrict__ dst,
                                 int R, int C) {
    int idx = blockIdx.x * blockDim.x + threadIdx.x;
    if (idx >= R * C) return;
    int k = idx % C, n = idx / C;
    dst[(size_t)k * R + n] = src[(size_t)n * C + k];
}

// ---- Register-blocked tiled GEMM: H(fp16)[n][o] = dot(act(A[n][:]), WT[:][o]) ----
template <int K, int OUT, int TN, bool ELU>
__global__ __launch_bounds__(256) void gemm_fused(
        const float* __restrict__ A, const float* __restrict__ WT,
        const float* __restrict__ asrc, const float* __restrict__ adst,
        u16* __restrict__ H, float* __restrict__ s_out, float* __restrict__ d_out_,
        int N) {
    constexpr int BM = 128, BK = 32, TM = 8;
    constexpr int BMP = BM + 4;
    const int t = threadIdx.x;
    const int tr = t >> 4, tc = t & 15;
    const int n0 = blockIdx.x * BM;
    const int nrow = min(BM, N - n0);

    __shared__ float As[BK][BMP];
    __shared__ float Bs[BK][OUT];

    float acc[TM][TN];
#pragma unroll
    for (int i = 0; i < TM; ++i)
#pragma unroll
        for (int j = 0; j < TN; ++j) acc[i][j] = 0.f;

    for (int k0 = 0; k0 < K; k0 += BK) {
#pragma unroll
        for (int it = 0; it < (BM * BK / 4) / 256; ++it) {
            int q = t + 256 * it;
            int m = q >> 3;
            int kq = q & 7;
            float4 v = make_float4(0.f, 0.f, 0.f, 0.f);
            if (m < nrow) v = *(const float4*)&A[(size_t)(n0 + m) * K + k0 + 4 * kq];
            if (ELU) {
                v.x = v.x > 0.f ? v.x : expm1f(v.x);
                v.y = v.y > 0.f ? v.y : expm1f(v.y);
                v.z = v.z > 0.f ? v.z : expm1f(v.z);
                v.w = v.w > 0.f ? v.w : expm1f(v.w);
            }
            As[4 * kq + 0][m] = v.x;
            As[4 * kq + 1][m] = v.y;
            As[4 * kq + 2][m] = v.z;
            As[4 * kq + 3][m] = v.w;
        }
#pragma unroll
        for (int it = 0; it < (BK * OUT / 4) / 256; ++it) {
            int q = t + 256 * it;
            int kk = q / (OUT / 4);
            int j = q % (OUT / 4);
            *(float4*)&Bs[kk][4 * j] = *(const float4*)&WT[(size_t)(k0 + kk) * OUT + 4 * j];
        }
        __syncthreads();

        for (int k = 0; k < BK; ++k) {
            float a[TM], b[TN];
            *(float4*)&a[0] = *(const float4*)&As[k][TM * tr];
            *(float4*)&a[4] = *(const float4*)&As[k][TM * tr + 4];
#pragma unroll
            for (int j4 = 0; j4 < TN / 4; ++j4)
                *(float4*)&b[4 * j4] = *(const float4*)&Bs[k][TN * tc + 4 * j4];
#pragma unroll
            for (int i = 0; i < TM; ++i)
#pragma unroll
                for (int j = 0; j < TN; ++j) acc[i][j] = fmaf(a[i], b[j], acc[i][j]);
        }
        __syncthreads();
    }

    // epilogue: fp16 H rows + fused score dots (f32 accs)
#pragma unroll
    for (int i = 0; i < TM; ++i) {
        int m = TM * tr + i;
        if (m < nrow) {
            u32 pk[TN / 2];
#pragma unroll
            for (int j2 = 0; j2 < TN / 2; ++j2)
                pk[j2] = pack_h2(acc[i][2 * j2], acc[i][2 * j2 + 1]);
            if (TN == 8)
                *(uint4*)&H[(size_t)(n0 + m) * OUT + TN * tc] = *(uint4*)pk;
            else
                *(uint2*)&H[(size_t)(n0 + m) * OUT + TN * tc] = *(uint2*)pk;
        }
    }
#pragma unroll
    for (int i = 0; i < TM; ++i) {
        float vs = 0.f, vd = 0.f;
#pragma unroll
        for (int j = 0; j < TN; ++j) {
            vs = fmaf(acc[i][j], asrc[TN * tc + j], vs);
            vd = fmaf(acc[i][j], adst[TN * tc + j], vd);
        }
#pragma unroll
        for (int off = 8; off >= 1; off >>= 1) {
            vs += __shfl_down(vs, off, 16);
            vd += __shfl_down(vd, off, 16);
        }
        int m = TM * tr + i;
        if (tc == 0 && m < nrow) {
            s_out[n0 + m] = vs;
            d_out_[n0 + m] = vd;
        }
    }
}

// ---- CSR build: histogram -> scan -> scatter (verified versions) ----
__global__ void hist_kernel(const int* __restrict__ row, int* __restrict__ cnt, int E) {
    int i = blockIdx.x * blockDim.x + threadIdx.x;
    if (i < E) atomicAdd(&cnt[row[i]], 1);
}

__global__ __launch_bounds__(1024) void scan1_kernel(const int* __restrict__ cnt,
                                                     int* __restrict__ exc,
                                                     int* __restrict__ bsum, int N) {
    __shared__ int s[1024];
    const int t = threadIdx.x;
    const int i = blockIdx.x * 1024 + t;
    int v = (i < N) ? cnt[i] : 0;
    s[t] = v;
    __syncthreads();
    for (int off = 1; off < 1024; off <<= 1) {
        int x = (t >= off) ? s[t - off] : 0;
        __syncthreads();
        s[t] += x;
        __syncthreads();
    }
    if (i < N) exc[i] = s[t] - v;
    if (t == 1023) bsum[blockIdx.x] = s[t];
}

__global__ void scan2_kernel(int* __restrict__ bsum, int* __restrict__ boff, int nb) {
    if (threadIdx.x == 0 && blockIdx.x == 0) {
        int acc = 0;
        for (int i = 0; i < nb; ++i) { boff[i] = acc; acc += bsum[i]; }
    }
}

__global__ void scan3_kernel(int* __restrict__ rp, const int* __restrict__ boff,
                             int N, int E) {
    int i = blockIdx.x * blockDim.x + threadIdx.x;
    if (i < N) rp[i] += boff[i >> 10];
    if (i == 0) rp[N] = E;
}

__global__ void scatter_kernel(const int* __restrict__ row, const int* __restrict__ col,
                               const int* __restrict__ rp, int* __restrict__ off,
                               int* __restrict__ cs, int E) {
    int i = blockIdx.x * blockDim.x + threadIdx.x;
    if (i >= E) return;
    int r = row[i];
    int p = rp[r] + atomicAdd(&off[r], 1);
    cs[p] = col[i];
}

// ---- Fused GAT layer over CSR, fp16 gather, shfl-broadcast phase 3 ----
template <int D>
__global__ __launch_bounds__(256) void gat_csr_f16(
        const int* __restrict__ rp, const int* __restrict__ cs,
        const float* __restrict__ s, const float* __restrict__ d,
        const u32* __restrict__ fp,  // packed fp16 pairs, row stride D/2
        float* __restrict__ out, int N) {
    const int wid = threadIdx.x >> 6;
    const int lane = threadIdx.x & 63;
    const int r = blockIdx.x * 4 + wid;
    if (r >= N) return;
    const int start = rp[r], end = rp[r + 1];
    const int len = end - start;

    float acc0 = 0.f, acc1 = 0.f;

    if (len > 0 && len <= 64) {
        const float sr = s[r];
        // per-lane edge data (masked-lane softmax == wave-strided form for len<=64)
        int c_l = 0;
        float e_l = -INFINITY;
        if (lane < len) {
            c_l = cs[start + lane];
            float e = sr + d[c_l];
            e_l = (e >= 0.f) ? e : NEG_SLOPE * e;
        }
        float m = e_l;
#pragma unroll
        for (int off = 32; off >= 1; off >>= 1) m = fmaxf(m, __shfl_xor(m, off));
        float ex_l = (lane < len) ? __expf(e_l - m) : 0.f;
        float den = ex_l;
#pragma unroll
        for (int off = 32; off >= 1; off >>= 1) den += __shfl_xor(den, off);
        const float a_l = ex_l * (1.f / den);

        // phase 3: shfl-broadcast (c_j, a_j); 4 gathers in flight per chunk
        int j = 0;
        for (; j + 4 <= len; j += 4) {
            int c0 = __shfl(c_l, j), c1 = __shfl(c_l, j + 1);
            int c2 = __shfl(c_l, j + 2), c3 = __shfl(c_l, j + 3);
            float a0 = __shfl(a_l, j), a1 = __shfl(a_l, j + 1);
            float a2 = __shfl(a_l, j + 2), a3 = __shfl(a_l, j + 3);
            if (D == 128) {
                u32 v0 = fp[(size_t)c0 * 64 + lane];
                u32 v1 = fp[(size_t)c1 * 64 + lane];
                u32 v2 = fp[(size_t)c2 * 64 + lane];
                u32 v3 = fp[(size_t)c3 * 64 + lane];
                float2 f0 = unpack_h2(v0), f1 = unpack_h2(v1);
                float2 f2 = unpack_h2(v2), f3 = unpack_h2(v3);
                acc0 = fmaf(a0, f0.x, acc0); acc1 = fmaf(a0, f0.y, acc1);
                acc0 = fmaf(a1, f1.x, acc0); acc1 = fmaf(a1, f1.y, acc1);
                acc0 = fmaf(a2, f2.x, acc0); acc1 = fmaf(a2, f2.y, acc1);
                acc0 = fmaf(a3, f3.x, acc0); acc1 = fmaf(a3, f3.y, acc1);
            } else {
                u32 v0 = fp[(size_t)c0 * 32 + (lane >> 1)];
                u32 v1 = fp[(size_t)c1 * 32 + (lane >> 1)];
                u32 v2 = fp[(size_t)c2 * 32 + (lane >> 1)];
                u32 v3 = fp[(size_t)c3 * 32 + (lane >> 1)];
                float2 f0 = unpack_h2(v0), f1 = unpack_h2(v1);
                float2 f2 = unpack_h2(v2), f3 = unpack_h2(v3);
                acc0 = fmaf(a0, (lane & 1) ? f0.y : f0.x, acc0);
                acc0 = fmaf(a1, (lane & 1) ? f1.y : f1.x, acc0);
                acc0 = fmaf(a2, (lane & 1) ? f2.y : f2.x, acc0);
                acc0 = fmaf(a3, (lane & 1) ? f3.y : f3.x, acc0);
            }
        }
        for (; j < len; ++j) {
            int cj = __shfl(c_l, j);
            float aj = __shfl(a_l, j);
            if (D == 128) {
                float2 v = unpack_h2(fp[(size_t)cj * 64 + lane]);
                acc0 = fmaf(aj, v.x, acc0);
                acc1 = fmaf(aj, v.y, acc1);
            } else {
                float2 v = unpack_h2(fp[(size_t)cj * 32 + (lane >> 1)]);
                acc0 = fmaf(aj, (lane & 1) ? v.y : v.x, acc0);
            }
        }
    } else if (len > 64) {
        // generic long-row path: round-6 verified code, unchanged
        const float sr = s[r];
        float m = -INFINITY;
        for (int j = start + lane; j < end; j += 64) {
            float e = sr + d[cs[j]];
            e = (e >= 0.f) ? e : NEG_SLOPE * e;
            m = fmaxf(m, e);
        }
#pragma unroll
        for (int off = 32; off >= 1; off >>= 1) m = fmaxf(m, __shfl_xor(m, off));
        float den = 0.f;
        for (int j = start + lane; j < end; j += 64) {
            float e = sr + d[cs[j]];
            e = (e >= 0.f) ? e : NEG_SLOPE * e;
            den += __expf(e - m);
        }
#pragma unroll
        for (int off = 32; off >= 1; off >>= 1) den += __shfl_xor(den, off);
        const float inv = 1.f / den;
        for (int j = start; j < end; ++j) {
            int c = __builtin_amdgcn_readfirstlane(cs[j]);
            float e = sr + d[c];
            e = (e >= 0.f) ? e : NEG_SLOPE * e;
            float alpha = __expf(e - m) * inv;
            if (D == 128) {
                float2 v = unpack_h2(fp[(size_t)c * 64 + lane]);
                acc0 = fmaf(alpha, v.x, acc0);
                acc1 = fmaf(alpha, v.y, acc1);
            } else {
                float2 v = unpack_h2(fp[(size_t)c * 32 + (lane >> 1)]);
                acc0 = fmaf(alpha, (lane & 1) ? v.y : v.x, acc0);
            }
        }
    }

    if (D == 128)
        *(float2*)&out[(size_t)r * D + 2 * lane] = make_float2(acc0, acc1);
    else
        out[(size_t)r * D + lane] = acc0;
}

extern "C" void kernel_launch(void* const* d_in, const int* in_sizes, int n_in,
                              void* d_out, int out_size, void* d_ws, size_t ws_size,
                              hipStream_t stream) {
    const float* x   = (const float*)d_in[0];
    const int*   edg = (const int*)d_in[1];
    const float* W1  = (const float*)d_in[2];
    const float* W2  = (const float*)d_in[3];
    const float* as1 = (const float*)d_in[4];
    const float* ad1 = (const float*)d_in[5];
    const float* as2 = (const float*)d_in[6];
    const float* ad2 = (const float*)d_in[7];

    const int N = in_sizes[0] / 256;
    const int E = in_sizes[1] / 2;
    const int* row = edg;
    const int* col = edg + E;

    // Workspace layout
    char* p = (char*)d_ws;
    u16* h1f = (u16*)p;     p += (size_t)N * 128 * 2;   // layer-1 features, fp16
    u16* h2f = (u16*)p;     p += (size_t)N * 64 * 2;    // layer-2 features, fp16
    float* g1 = (float*)p;  p += (size_t)N * 128 * 4;   // GAT1 output, f32
    float* sm = (float*)p;  p += (size_t)N * 4 * 4;     // s1,d1,s2,d2
    float* s1 = sm + (size_t)N * 0;
    float* d1 = sm + (size_t)N * 1;
    float* s2 = sm + (size_t)N * 2;
    float* d2 = sm + (size_t)N * 3;
    float* W1T = (float*)p; p += (size_t)256 * 128 * 4;
    float* W2T = (float*)p; p += (size_t)128 * 64 * 4;
    int* cnt = (int*)p;     p += (size_t)N * 4;
    int* off = (int*)p;     p += (size_t)N * 4;
    int* rp  = (int*)p;     p += (size_t)(N + 1) * 4;
    int* bsum = (int*)p;    p += 1024 * 4;
    int* boff = (int*)p;    p += 1024 * 4;
    int* cs  = (int*)p;     p += (size_t)E * 4;

    // Only the histogram + cursors need zeroing (everything else fully written)
    hipMemsetAsync(cnt, 0, (size_t)N * 2 * 4, stream);

    transpose_kernel<<<(128 * 256 + 255) / 256, 256, 0, stream>>>(W1, W1T, 128, 256);
    transpose_kernel<<<(64 * 128 + 255) / 256, 256, 0, stream>>>(W2, W2T, 64, 128);

    const int EB = (E + 255) / 256;
    const int GB = (N + 127) / 128;
    const int SB = (N + 1023) / 1024;

    // CSR build (row shared by both layers)
    hist_kernel<<<EB, 256, 0, stream>>>(row, cnt, E);
    scan1_kernel<<<SB, 1024, 0, stream>>>(cnt, rp, bsum, N);
    scan2_kernel<<<1, 64, 0, stream>>>(bsum, boff, SB);
    scan3_kernel<<<(N + 256) / 256, 256, 0, stream>>>(rp, boff, N, E);
    scatter_kernel<<<EB, 256, 0, stream>>>(row, col, rp, off, cs, E);

    // Layer 1
    gemm_fused<256, 128, 8, false><<<GB, 256, 0, stream>>>(x, W1T, as1, ad1, h1f, s1, d1, N);
    gat_csr_f16<128><<<(N + 3) / 4, 256, 0, stream>>>(rp, cs, s1, d1, (const u32*)h1f, g1, N);

    // Layer 2 (ELU fused into GEMM2 A-staging)
    gemm_fused<128, 64, 4, true><<<GB, 256, 0, stream>>>(g1, W2T, as2, ad2, h2f, s2, d2, N);
    gat_csr_f16<64><<<(N + 3) / 4, 256, 0, stream>>>(rp, cs, s2, d2, (const u32*)h2f,
                                                     (float*)d_out, N);
}

// Round 8
// 394.305 us; speedup vs baseline: 1.7155x; 1.1430x over previous
//
#include <hip/hip_runtime.h>
#include <hip/hip_fp16.h>
#include <math.h>

#define NEG_SLOPE 0.2f
typedef unsigned int u32;
typedef unsigned short u16;

__device__ __forceinline__ u32 pack_h2(float a, float b) {
    __half2 h = __floats2half2_rn(a, b);
    return *(u32*)&h;
}
__device__ __forceinline__ float2 unpack_h2(u32 v) {
    return __half22float2(*(const __half2*)&v);
}

// ---- tiny one-time transpose: src [R][C] -> dst [C][R] ----
__global__ void transpose_kernel(const float* __restrict__ src, float* __restrict__ dst,
                                 int R, int C) {
    int idx = blockIdx.x * blockDim.x + threadIdx.x;
    if (idx >= R * C) return;
    int k = idx % C, n = idx / C;
    dst[(size_t)k * R + n] = src[(size_t)n * C + k];
}

// ---- Register-blocked tiled GEMM: H(fp16)[n][o] = dot(act(A[n][:]), WT[:][o]) ----
template <int K, int OUT, int TN, bool ELU>
__global__ __launch_bounds__(256) void gemm_fused(
        const float* __restrict__ A, const float* __restrict__ WT,
        const float* __restrict__ asrc, const float* __restrict__ adst,
        u16* __restrict__ H, float* __restrict__ s_out, float* __restrict__ d_out_,
        int N) {
    constexpr int BM = 128, BK = 32, TM = 8;
    constexpr int BMP = BM + 4;
    const int t = threadIdx.x;
    const int tr = t >> 4, tc = t & 15;
    const int n0 = blockIdx.x * BM;
    const int nrow = min(BM, N - n0);

    __shared__ float As[BK][BMP];
    __shared__ float Bs[BK][OUT];

    float acc[TM][TN];
#pragma unroll
    for (int i = 0; i < TM; ++i)
#pragma unroll
        for (int j = 0; j < TN; ++j) acc[i][j] = 0.f;

    for (int k0 = 0; k0 < K; k0 += BK) {
#pragma unroll
        for (int it = 0; it < (BM * BK / 4) / 256; ++it) {
            int q = t + 256 * it;
            int m = q >> 3;
            int kq = q & 7;
            float4 v = make_float4(0.f, 0.f, 0.f, 0.f);
            if (m < nrow) v = *(const float4*)&A[(size_t)(n0 + m) * K + k0 + 4 * kq];
            if (ELU) {
                v.x = v.x > 0.f ? v.x : expm1f(v.x);
                v.y = v.y > 0.f ? v.y : expm1f(v.y);
                v.z = v.z > 0.f ? v.z : expm1f(v.z);
                v.w = v.w > 0.f ? v.w : expm1f(v.w);
            }
            As[4 * kq + 0][m] = v.x;
            As[4 * kq + 1][m] = v.y;
            As[4 * kq + 2][m] = v.z;
            As[4 * kq + 3][m] = v.w;
        }
#pragma unroll
        for (int it = 0; it < (BK * OUT / 4) / 256; ++it) {
            int q = t + 256 * it;
            int kk = q / (OUT / 4);
            int j = q % (OUT / 4);
            *(float4*)&Bs[kk][4 * j] = *(const float4*)&WT[(size_t)(k0 + kk) * OUT + 4 * j];
        }
        __syncthreads();

        for (int k = 0; k < BK; ++k) {
            float a[TM], b[TN];
            *(float4*)&a[0] = *(const float4*)&As[k][TM * tr];
            *(float4*)&a[4] = *(const float4*)&As[k][TM * tr + 4];
#pragma unroll
            for (int j4 = 0; j4 < TN / 4; ++j4)
                *(float4*)&b[4 * j4] = *(const float4*)&Bs[k][TN * tc + 4 * j4];
#pragma unroll
            for (int i = 0; i < TM; ++i)
#pragma unroll
                for (int j = 0; j < TN; ++j) acc[i][j] = fmaf(a[i], b[j], acc[i][j]);
        }
        __syncthreads();
    }

    // epilogue: fp16 H rows + fused score dots (f32 accs)
#pragma unroll
    for (int i = 0; i < TM; ++i) {
        int m = TM * tr + i;
        if (m < nrow) {
            u32 pk[TN / 2];
#pragma unroll
            for (int j2 = 0; j2 < TN / 2; ++j2)
                pk[j2] = pack_h2(acc[i][2 * j2], acc[i][2 * j2 + 1]);
            if (TN == 8)
                *(uint4*)&H[(size_t)(n0 + m) * OUT + TN * tc] = *(uint4*)pk;
            else
                *(uint2*)&H[(size_t)(n0 + m) * OUT + TN * tc] = *(uint2*)pk;
        }
    }
#pragma unroll
    for (int i = 0; i < TM; ++i) {
        float vs = 0.f, vd = 0.f;
#pragma unroll
        for (int j = 0; j < TN; ++j) {
            vs = fmaf(acc[i][j], asrc[TN * tc + j], vs);
            vd = fmaf(acc[i][j], adst[TN * tc + j], vd);
        }
#pragma unroll
        for (int off = 8; off >= 1; off >>= 1) {
            vs += __shfl_down(vs, off, 16);
            vd += __shfl_down(vd, off, 16);
        }
        int m = TM * tr + i;
        if (tc == 0 && m < nrow) {
            s_out[n0 + m] = vs;
            d_out_[n0 + m] = vd;
        }
    }
}

// ---- CSR build: histogram -> scan (verified) ----
__global__ void hist_kernel(const int* __restrict__ row, int* __restrict__ cnt, int E) {
    int i = blockIdx.x * blockDim.x + threadIdx.x;
    if (i < E) atomicAdd(&cnt[row[i]], 1);
}

__global__ __launch_bounds__(1024) void scan1_kernel(const int* __restrict__ cnt,
                                                     int* __restrict__ exc,
                                                     int* __restrict__ bsum, int N) {
    __shared__ int s[1024];
    const int t = threadIdx.x;
    const int i = blockIdx.x * 1024 + t;
    int v = (i < N) ? cnt[i] : 0;
    s[t] = v;
    __syncthreads();
    for (int off = 1; off < 1024; off <<= 1) {
        int x = (t >= off) ? s[t - off] : 0;
        __syncthreads();
        s[t] += x;
        __syncthreads();
    }
    if (i < N) exc[i] = s[t] - v;
    if (t == 1023) bsum[blockIdx.x] = s[t];
}

__global__ void scan2_kernel(int* __restrict__ bsum, int* __restrict__ boff, int nb) {
    if (threadIdx.x == 0 && blockIdx.x == 0) {
        int acc = 0;
        for (int i = 0; i < nb; ++i) { boff[i] = acc; acc += bsum[i]; }
    }
}

__global__ void scan3_kernel(int* __restrict__ rp, const int* __restrict__ boff,
                             int N, int E) {
    int i = blockIdx.x * blockDim.x + threadIdx.x;
    if (i < N) rp[i] += boff[i >> 10];
    if (i == 0) rp[N] = E;
}

// ---- Pass A: bin edges by bucket (row>>9) with LDS staging, coalesced flush ----
#define BKT_CAP 12288
__global__ __launch_bounds__(256) void bin_kernel(
        const int* __restrict__ row, const int* __restrict__ col,
        int* __restrict__ gcnt, uint2* __restrict__ staging, int E, int NB) {
    __shared__ int hist[256];
    __shared__ int scn[256];
    __shared__ int start[256];
    __shared__ int cursor[256];
    __shared__ int gbase[256];
    __shared__ uint2 binned[4096];
    const int t = threadIdx.x;
    const int base = blockIdx.x * 4096;
    const int cnt = min(4096, E - base);

    hist[t] = 0;
    __syncthreads();

    int myr[16], myc[16];
#pragma unroll
    for (int it = 0; it < 16; ++it) {
        int q = t + 256 * it;
        if (q < cnt) {
            myr[it] = row[base + q];
            myc[it] = col[base + q];
            atomicAdd(&hist[myr[it] >> 9], 1);
        }
    }
    __syncthreads();

    // block-wide Hillis-Steele scan (same pattern as verified scan1)
    int v = hist[t];
    scn[t] = v;
    __syncthreads();
    for (int off = 1; off < 256; off <<= 1) {
        int x = (t >= off) ? scn[t - off] : 0;
        __syncthreads();
        scn[t] += x;
        __syncthreads();
    }
    start[t] = scn[t] - v;   // exclusive
    cursor[t] = scn[t] - v;
    __syncthreads();

#pragma unroll
    for (int it = 0; it < 16; ++it) {
        int q = t + 256 * it;
        if (q < cnt) {
            int b = myr[it] >> 9;
            int slot = atomicAdd(&cursor[b], 1);
            binned[slot] = make_uint2((u32)myr[it], (u32)myc[it]);
        }
    }
    __syncthreads();

    if (t < NB && hist[t] > 0) gbase[t] = atomicAdd(&gcnt[t], hist[t]);
    __syncthreads();

    for (int q = t; q < cnt; q += 256) {
        uint2 e = binned[q];
        int b = (int)(e.x >> 9);
        int pos = gbase[b] + (q - start[b]);
        staging[(size_t)b * BKT_CAP + pos] = e;
    }
}

// ---- Pass B: one block per bucket; scatter into cs within a ~32KB window ----
__global__ __launch_bounds__(256) void csr_scatter2(
        const uint2* __restrict__ staging, const int* __restrict__ gcnt,
        const int* __restrict__ rp, int* __restrict__ cs) {
    __shared__ int cur[512];
    const int b = blockIdx.x;
    const int t = threadIdx.x;
    cur[t] = 0;
    cur[t + 256] = 0;
    __syncthreads();
    const int n = gcnt[b];
    for (int i = t; i < n; i += 256) {
        uint2 e = staging[(size_t)b * BKT_CAP + i];
        int p = rp[e.x] + atomicAdd(&cur[e.x & 511], 1);
        cs[p] = (int)e.y;
    }
}

// ---- Fused GAT layer over CSR, fp16 gather, shfl-broadcast phase 3 ----
template <int D>
__global__ __launch_bounds__(256) void gat_csr_f16(
        const int* __restrict__ rp, const int* __restrict__ cs,
        const float* __restrict__ s, const float* __restrict__ d,
        const u32* __restrict__ fp,  // packed fp16 pairs, row stride D/2
        float* __restrict__ out, int N) {
    const int wid = threadIdx.x >> 6;
    const int lane = threadIdx.x & 63;
    const int r = blockIdx.x * 4 + wid;
    if (r >= N) return;
    const int start = rp[r], end = rp[r + 1];
    const int len = end - start;

    float acc0 = 0.f, acc1 = 0.f;

    if (len > 0 && len <= 64) {
        const float sr = s[r];
        int c_l = 0;
        float e_l = -INFINITY;
        if (lane < len) {
            c_l = cs[start + lane];
            float e = sr + d[c_l];
            e_l = (e >= 0.f) ? e : NEG_SLOPE * e;
        }
        float m = e_l;
#pragma unroll
        for (int off = 32; off >= 1; off >>= 1) m = fmaxf(m, __shfl_xor(m, off));
        float ex_l = (lane < len) ? __expf(e_l - m) : 0.f;
        float den = ex_l;
#pragma unroll
        for (int off = 32; off >= 1; off >>= 1) den += __shfl_xor(den, off);
        const float a_l = ex_l * (1.f / den);

        int j = 0;
        for (; j + 4 <= len; j += 4) {
            int c0 = __shfl(c_l, j), c1 = __shfl(c_l, j + 1);
            int c2 = __shfl(c_l, j + 2), c3 = __shfl(c_l, j + 3);
            float a0 = __shfl(a_l, j), a1 = __shfl(a_l, j + 1);
            float a2 = __shfl(a_l, j + 2), a3 = __shfl(a_l, j + 3);
            if (D == 128) {
                u32 v0 = fp[(size_t)c0 * 64 + lane];
                u32 v1 = fp[(size_t)c1 * 64 + lane];
                u32 v2 = fp[(size_t)c2 * 64 + lane];
                u32 v3 = fp[(size_t)c3 * 64 + lane];
                float2 f0 = unpack_h2(v0), f1 = unpack_h2(v1);
                float2 f2 = unpack_h2(v2), f3 = unpack_h2(v3);
                acc0 = fmaf(a0, f0.x, acc0); acc1 = fmaf(a0, f0.y, acc1);
                acc0 = fmaf(a1, f1.x, acc0); acc1 = fmaf(a1, f1.y, acc1);
                acc0 = fmaf(a2, f2.x, acc0); acc1 = fmaf(a2, f2.y, acc1);
                acc0 = fmaf(a3, f3.x, acc0); acc1 = fmaf(a3, f3.y, acc1);
            } else {
                u32 v0 = fp[(size_t)c0 * 32 + (lane >> 1)];
                u32 v1 = fp[(size_t)c1 * 32 + (lane >> 1)];
                u32 v2 = fp[(size_t)c2 * 32 + (lane >> 1)];
                u32 v3 = fp[(size_t)c3 * 32 + (lane >> 1)];
                float2 f0 = unpack_h2(v0), f1 = unpack_h2(v1);
                float2 f2 = unpack_h2(v2), f3 = unpack_h2(v3);
                acc0 = fmaf(a0, (lane & 1) ? f0.y : f0.x, acc0);
                acc0 = fmaf(a1, (lane & 1) ? f1.y : f1.x, acc0);
                acc0 = fmaf(a2, (lane & 1) ? f2.y : f2.x, acc0);
                acc0 = fmaf(a3, (lane & 1) ? f3.y : f3.x, acc0);
            }
        }
        for (; j < len; ++j) {
            int cj = __shfl(c_l, j);
            float aj = __shfl(a_l, j);
            if (D == 128) {
                float2 v = unpack_h2(fp[(size_t)cj * 64 + lane]);
                acc0 = fmaf(aj, v.x, acc0);
                acc1 = fmaf(aj, v.y, acc1);
            } else {
                float2 v = unpack_h2(fp[(size_t)cj * 32 + (lane >> 1)]);
                acc0 = fmaf(aj, (lane & 1) ? v.y : v.x, acc0);
            }
        }
    } else if (len > 64) {
        const float sr = s[r];
        float m = -INFINITY;
        for (int j = start + lane; j < end; j += 64) {
            float e = sr + d[cs[j]];
            e = (e >= 0.f) ? e : NEG_SLOPE * e;
            m = fmaxf(m, e);
        }
#pragma unroll
        for (int off = 32; off >= 1; off >>= 1) m = fmaxf(m, __shfl_xor(m, off));
        float den = 0.f;
        for (int j = start + lane; j < end; j += 64) {
            float e = sr + d[cs[j]];
            e = (e >= 0.f) ? e : NEG_SLOPE * e;
            den += __expf(e - m);
        }
#pragma unroll
        for (int off = 32; off >= 1; off >>= 1) den += __shfl_xor(den, off);
        const float inv = 1.f / den;
        for (int j = start; j < end; ++j) {
            int c = __builtin_amdgcn_readfirstlane(cs[j]);
            float e = sr + d[c];
            e = (e >= 0.f) ? e : NEG_SLOPE * e;
            float alpha = __expf(e - m) * inv;
            if (D == 128) {
                float2 v = unpack_h2(fp[(size_t)c * 64 + lane]);
                acc0 = fmaf(alpha, v.x, acc0);
                acc1 = fmaf(alpha, v.y, acc1);
            } else {
                float2 v = unpack_h2(fp[(size_t)c * 32 + (lane >> 1)]);
                acc0 = fmaf(alpha, (lane & 1) ? v.y : v.x, acc0);
            }
        }
    }

    if (D == 128)
        *(float2*)&out[(size_t)r * D + 2 * lane] = make_float2(acc0, acc1);
    else
        out[(size_t)r * D + lane] = acc0;
}

extern "C" void kernel_launch(void* const* d_in, const int* in_sizes, int n_in,
                              void* d_out, int out_size, void* d_ws, size_t ws_size,
                              hipStream_t stream) {
    const float* x   = (const float*)d_in[0];
    const int*   edg = (const int*)d_in[1];
    const float* W1  = (const float*)d_in[2];
    const float* W2  = (const float*)d_in[3];
    const float* as1 = (const float*)d_in[4];
    const float* ad1 = (const float*)d_in[5];
    const float* as2 = (const float*)d_in[6];
    const float* ad2 = (const float*)d_in[7];

    const int N = in_sizes[0] / 256;
    const int E = in_sizes[1] / 2;
    const int* row = edg;
    const int* col = edg + E;
    const int NB = (N + 511) / 512;  // buckets of 512 rows (<=256 for N<=131072)

    // Workspace layout
    char* p = (char*)d_ws;
    u16* h1f = (u16*)p;     p += (size_t)N * 128 * 2;   // layer-1 features, fp16
    u16* h2f = (u16*)p;     p += (size_t)N * 64 * 2;    // layer-2 features, fp16
    // staging (dead before g1 written) aliases g1
    char* g1s = p;
    float* g1 = (float*)g1s;
    uint2* staging = (uint2*)g1s;
    size_t g1_bytes = (size_t)N * 128 * 4;
    size_t stg_bytes = (size_t)NB * BKT_CAP * 8;
    p += (g1_bytes > stg_bytes) ? g1_bytes : stg_bytes;
    float* sm = (float*)p;  p += (size_t)N * 4 * 4;     // s1,d1,s2,d2
    float* s1 = sm + (size_t)N * 0;
    float* d1 = sm + (size_t)N * 1;
    float* s2 = sm + (size_t)N * 2;
    float* d2 = sm + (size_t)N * 3;
    float* W1T = (float*)p; p += (size_t)256 * 128 * 4;
    float* W2T = (float*)p; p += (size_t)128 * 64 * 4;
    int* cnt = (int*)p;     p += (size_t)N * 4;         // row histogram (zeroed)
    int* gcnt = (int*)p;    p += 256 * 4;               // bucket cursors (zeroed)
    int* rp  = (int*)p;     p += (size_t)(N + 1) * 4;   // CSR row_ptr
    int* bsum = (int*)p;    p += 1024 * 4;
    int* boff = (int*)p;    p += 1024 * 4;
    int* cs  = (int*)p;     p += (size_t)E * 4;         // CSR col indices

    hipMemsetAsync(cnt, 0, ((size_t)N + 256) * 4, stream);  // cnt + gcnt

    transpose_kernel<<<(128 * 256 + 255) / 256, 256, 0, stream>>>(W1, W1T, 128, 256);
    transpose_kernel<<<(64 * 128 + 255) / 256, 256, 0, stream>>>(W2, W2T, 64, 128);

    const int EB = (E + 255) / 256;
    const int GB = (N + 127) / 128;
    const int SB = (N + 1023) / 1024;

    // CSR build: rp via verified hist+scan; cs via 2-level binned scatter
    hist_kernel<<<EB, 256, 0, stream>>>(row, cnt, E);
    scan1_kernel<<<SB, 1024, 0, stream>>>(cnt, rp, bsum, N);
    scan2_kernel<<<1, 64, 0, stream>>>(bsum, boff, SB);
    scan3_kernel<<<(N + 256) / 256, 256, 0, stream>>>(rp, boff, N, E);
    bin_kernel<<<(E + 4095) / 4096, 256, 0, stream>>>(row, col, gcnt, staging, E, NB);
    csr_scatter2<<<NB, 256, 0, stream>>>(staging, gcnt, rp, cs);

    // Layer 1
    gemm_fused<256, 128, 8, false><<<GB, 256, 0, stream>>>(x, W1T, as1, ad1, h1f, s1, d1, N);
    gat_csr_f16<128><<<(N + 3) / 4, 256, 0, stream>>>(rp, cs, s1, d1, (const u32*)h1f, g1, N);

    // Layer 2 (ELU fused into GEMM2 A-staging)
    gemm_fused<128, 64, 4, true><<<GB, 256, 0, stream>>>(g1, W2T, as2, ad2, h2f, s2, d2, N);
    gat_csr_f16<64><<<(N + 3) / 4, 256, 0, stream>>>(rp, cs, s2, d2, (const u32*)h2f,
                                                     (float*)d_out, N);
}

// Round 9
// 327.617 us; speedup vs baseline: 2.0647x; 1.2036x over previous
//
#include <hip/hip_runtime.h>
#include <hip/hip_fp16.h>
#include <math.h>

#define NEG_SLOPE 0.2f
typedef unsigned int u32;
typedef unsigned short u16;
typedef _Float16 f16;
typedef __attribute__((ext_vector_type(8))) _Float16 f16x8;
typedef __attribute__((ext_vector_type(4))) float f32x4;

__device__ __forceinline__ float2 unpack_h2(u32 v) {
    return __half22float2(*(const __half2*)&v);
}

// ---- one-time f32 -> fp16 weight convert (same layout) ----
__global__ void convert_f16_kernel(const float* __restrict__ src, f16* __restrict__ dst,
                                   int n) {
    int i = blockIdx.x * blockDim.x + threadIdx.x;
    if (i < n) dst[i] = (f16)src[i];
}

// ---- MFMA fp16 GEMM: H[n][o] = dot(act(A[n][:]), W[o][:]); fused score dots ----
// W given as fp16 [OUT][K] row-major (= B^T rows). 4 waves, BM=128, BK=32.
template <int K, int OUT, bool ELU>
__global__ __launch_bounds__(256) void gemm_mfma(
        const float* __restrict__ A, const f16* __restrict__ WH,
        const float* __restrict__ asrc, const float* __restrict__ adst,
        f16* __restrict__ H, float* __restrict__ s_out, float* __restrict__ d_out_,
        int N) {
    constexpr int BM = 128, BK = 32;
    constexpr int LDA = 40;          // fp16 elems per LDS row (80 B: 16B-aligned, 2-way banks)
    constexpr int NREP = OUT / 16;
    __shared__ f16 As[BM * LDA];
    __shared__ f16 Bs[OUT * LDA];
    const int t = threadIdx.x;
    const int w = t >> 6, lane = t & 63;
    const int r16 = lane & 15, g = lane >> 4;  // frag row/col, k-group
    const int n0 = blockIdx.x * BM;

    f32x4 acc[2][NREP];
#pragma unroll
    for (int i = 0; i < 2; ++i)
#pragma unroll
        for (int j = 0; j < NREP; ++j) acc[i][j] = (f32x4){0.f, 0.f, 0.f, 0.f};

    for (int k0 = 0; k0 < K; k0 += BK) {
        // stage A tile [BM][BK] f32->fp16 (ELU fused if requested)
#pragma unroll
        for (int it = 0; it < 4; ++it) {
            int q = t + 256 * it;
            int m = q >> 3, c = q & 7;
            int gr = n0 + m;
            float4 v = make_float4(0.f, 0.f, 0.f, 0.f);
            if (gr < N) v = *(const float4*)&A[(size_t)gr * K + k0 + 4 * c];
            if (ELU) {
                v.x = v.x > 0.f ? v.x : expm1f(v.x);
                v.y = v.y > 0.f ? v.y : expm1f(v.y);
                v.z = v.z > 0.f ? v.z : expm1f(v.z);
                v.w = v.w > 0.f ? v.w : expm1f(v.w);
            }
            f16 tmp[4] = {(f16)v.x, (f16)v.y, (f16)v.z, (f16)v.w};
            *(uint2*)&As[m * LDA + 4 * c] = *(uint2*)tmp;  // 8B aligned
        }
        // stage B tile: rows of WH (cols of B), 16B vector copies
        for (int q = t; q < OUT * 4; q += 256) {
            int ccol = q >> 2, ch = q & 3;
            *(uint4*)&Bs[ccol * LDA + 8 * ch] =
                *(const uint4*)&WH[(size_t)ccol * K + k0 + 8 * ch];
        }
        __syncthreads();

        f16x8 afr0 = *(const f16x8*)&As[(w * 32 + r16) * LDA + 8 * g];
        f16x8 afr1 = *(const f16x8*)&As[(w * 32 + 16 + r16) * LDA + 8 * g];
#pragma unroll
        for (int j = 0; j < NREP; ++j) {
            f16x8 bfr = *(const f16x8*)&Bs[(j * 16 + r16) * LDA + 8 * g];
            acc[0][j] = __builtin_amdgcn_mfma_f32_16x16x32_f16(afr0, bfr, acc[0][j], 0, 0, 0);
            acc[1][j] = __builtin_amdgcn_mfma_f32_16x16x32_f16(afr1, bfr, acc[1][j], 0, 0, 0);
        }
        __syncthreads();
    }

    // epilogue: fp16 H + fused score dots. C/D: col=lane&15, row=(lane>>4)*4+reg.
#pragma unroll
    for (int i = 0; i < 2; ++i) {
#pragma unroll
        for (int reg = 0; reg < 4; ++reg) {
            int m = n0 + w * 32 + i * 16 + g * 4 + reg;
            float vs = 0.f, vd = 0.f;
            if (m < N) {
#pragma unroll
                for (int j = 0; j < NREP; ++j) {
                    float val = acc[i][j][reg];
                    H[(size_t)m * OUT + j * 16 + r16] = (f16)val;
                    vs = fmaf(val, asrc[j * 16 + r16], vs);
                    vd = fmaf(val, adst[j * 16 + r16], vd);
                }
            }
#pragma unroll
            for (int off = 8; off >= 1; off >>= 1) {
                vs += __shfl_down(vs, off, 16);
                vd += __shfl_down(vd, off, 16);
            }
            if (r16 == 0 && m < N) {
                s_out[m] = vs;
                d_out_[m] = vd;
            }
        }
    }
}

// ---- CSR build: histogram -> scan (verified) ----
__global__ void hist_kernel(const int* __restrict__ row, int* __restrict__ cnt, int E) {
    int i = blockIdx.x * blockDim.x + threadIdx.x;
    if (i < E) atomicAdd(&cnt[row[i]], 1);
}

__global__ __launch_bounds__(1024) void scan1_kernel(const int* __restrict__ cnt,
                                                     int* __restrict__ exc,
                                                     int* __restrict__ bsum, int N) {
    __shared__ int s[1024];
    const int t = threadIdx.x;
    const int i = blockIdx.x * 1024 + t;
    int v = (i < N) ? cnt[i] : 0;
    s[t] = v;
    __syncthreads();
    for (int off = 1; off < 1024; off <<= 1) {
        int x = (t >= off) ? s[t - off] : 0;
        __syncthreads();
        s[t] += x;
        __syncthreads();
    }
    if (i < N) exc[i] = s[t] - v;
    if (t == 1023) bsum[blockIdx.x] = s[t];
}

__global__ void scan2_kernel(int* __restrict__ bsum, int* __restrict__ boff, int nb) {
    if (threadIdx.x == 0 && blockIdx.x == 0) {
        int acc = 0;
        for (int i = 0; i < nb; ++i) { boff[i] = acc; acc += bsum[i]; }
    }
}

__global__ void scan3_kernel(int* __restrict__ rp, const int* __restrict__ boff,
                             int N, int E) {
    int i = blockIdx.x * blockDim.x + threadIdx.x;
    if (i < N) rp[i] += boff[i >> 10];
    if (i == 0) rp[N] = E;
}

// ---- Pass A: bin edges by bucket (row>>9) with LDS staging, coalesced flush ----
#define BKT_CAP 12288
__global__ __launch_bounds__(256) void bin_kernel(
        const int* __restrict__ row, const int* __restrict__ col,
        int* __restrict__ gcnt, uint2* __restrict__ staging, int E, int NB) {
    __shared__ int hist[256];
    __shared__ int scn[256];
    __shared__ int start[256];
    __shared__ int cursor[256];
    __shared__ int gbase[256];
    __shared__ uint2 binned[4096];
    const int t = threadIdx.x;
    const int base = blockIdx.x * 4096;
    const int cnt = min(4096, E - base);

    hist[t] = 0;
    __syncthreads();

    int myr[16], myc[16];
#pragma unroll
    for (int it = 0; it < 16; ++it) {
        int q = t + 256 * it;
        if (q < cnt) {
            myr[it] = row[base + q];
            myc[it] = col[base + q];
            atomicAdd(&hist[myr[it] >> 9], 1);
        }
    }
    __syncthreads();

    int v = hist[t];
    scn[t] = v;
    __syncthreads();
    for (int off = 1; off < 256; off <<= 1) {
        int x = (t >= off) ? scn[t - off] : 0;
        __syncthreads();
        scn[t] += x;
        __syncthreads();
    }
    start[t] = scn[t] - v;
    cursor[t] = scn[t] - v;
    __syncthreads();

#pragma unroll
    for (int it = 0; it < 16; ++it) {
        int q = t + 256 * it;
        if (q < cnt) {
            int b = myr[it] >> 9;
            int slot = atomicAdd(&cursor[b], 1);
            binned[slot] = make_uint2((u32)myr[it], (u32)myc[it]);
        }
    }
    __syncthreads();

    if (t < NB && hist[t] > 0) gbase[t] = atomicAdd(&gcnt[t], hist[t]);
    __syncthreads();

    for (int q = t; q < cnt; q += 256) {
        uint2 e = binned[q];
        int b = (int)(e.x >> 9);
        int pos = gbase[b] + (q - start[b]);
        staging[(size_t)b * BKT_CAP + pos] = e;
    }
}

// ---- Pass B: one block per bucket; scatter into cs within a ~32KB window ----
__global__ __launch_bounds__(256) void csr_scatter2(
        const uint2* __restrict__ staging, const int* __restrict__ gcnt,
        const int* __restrict__ rp, int* __restrict__ cs) {
    __shared__ int cur[512];
    const int b = blockIdx.x;
    const int t = threadIdx.x;
    cur[t] = 0;
    cur[t + 256] = 0;
    __syncthreads();
    const int n = gcnt[b];
    for (int i = t; i < n; i += 256) {
        uint2 e = staging[(size_t)b * BKT_CAP + i];
        int p = rp[e.x] + atomicAdd(&cur[e.x & 511], 1);
        cs[p] = (int)e.y;
    }
}

// ---- Fused GAT layer over CSR, fp16 gather, shfl-broadcast phase 3 ----
template <int D>
__global__ __launch_bounds__(256) void gat_csr_f16(
        const int* __restrict__ rp, const int* __restrict__ cs,
        const float* __restrict__ s, const float* __restrict__ d,
        const u32* __restrict__ fp,  // packed fp16 pairs, row stride D/2
        float* __restrict__ out, int N) {
    const int wid = threadIdx.x >> 6;
    const int lane = threadIdx.x & 63;
    const int r = blockIdx.x * 4 + wid;
    if (r >= N) return;
    const int start = rp[r], end = rp[r + 1];
    const int len = end - start;

    float acc0 = 0.f, acc1 = 0.f;

    if (len > 0 && len <= 64) {
        const float sr = s[r];
        int c_l = 0;
        float e_l = -INFINITY;
        if (lane < len) {
            c_l = cs[start + lane];
            float e = sr + d[c_l];
            e_l = (e >= 0.f) ? e : NEG_SLOPE * e;
        }
        float m = e_l;
#pragma unroll
        for (int off = 32; off >= 1; off >>= 1) m = fmaxf(m, __shfl_xor(m, off));
        float ex_l = (lane < len) ? __expf(e_l - m) : 0.f;
        float den = ex_l;
#pragma unroll
        for (int off = 32; off >= 1; off >>= 1) den += __shfl_xor(den, off);
        const float a_l = ex_l * (1.f / den);

        int j = 0;
        for (; j + 4 <= len; j += 4) {
            int c0 = __shfl(c_l, j), c1 = __shfl(c_l, j + 1);
            int c2 = __shfl(c_l, j + 2), c3 = __shfl(c_l, j + 3);
            float a0 = __shfl(a_l, j), a1 = __shfl(a_l, j + 1);
            float a2 = __shfl(a_l, j + 2), a3 = __shfl(a_l, j + 3);
            if (D == 128) {
                u32 v0 = fp[(size_t)c0 * 64 + lane];
                u32 v1 = fp[(size_t)c1 * 64 + lane];
                u32 v2 = fp[(size_t)c2 * 64 + lane];
                u32 v3 = fp[(size_t)c3 * 64 + lane];
                float2 f0 = unpack_h2(v0), f1 = unpack_h2(v1);
                float2 f2 = unpack_h2(v2), f3 = unpack_h2(v3);
                acc0 = fmaf(a0, f0.x, acc0); acc1 = fmaf(a0, f0.y, acc1);
                acc0 = fmaf(a1, f1.x, acc0); acc1 = fmaf(a1, f1.y, acc1);
                acc0 = fmaf(a2, f2.x, acc0); acc1 = fmaf(a2, f2.y, acc1);
                acc0 = fmaf(a3, f3.x, acc0); acc1 = fmaf(a3, f3.y, acc1);
            } else {
                u32 v0 = fp[(size_t)c0 * 32 + (lane >> 1)];
                u32 v1 = fp[(size_t)c1 * 32 + (lane >> 1)];
                u32 v2 = fp[(size_t)c2 * 32 + (lane >> 1)];
                u32 v3 = fp[(size_t)c3 * 32 + (lane >> 1)];
                float2 f0 = unpack_h2(v0), f1 = unpack_h2(v1);
                float2 f2 = unpack_h2(v2), f3 = unpack_h2(v3);
                acc0 = fmaf(a0, (lane & 1) ? f0.y : f0.x, acc0);
                acc0 = fmaf(a1, (lane & 1) ? f1.y : f1.x, acc0);
                acc0 = fmaf(a2, (lane & 1) ? f2.y : f2.x, acc0);
                acc0 = fmaf(a3, (lane & 1) ? f3.y : f3.x, acc0);
            }
        }
        for (; j < len; ++j) {
            int cj = __shfl(c_l, j);
            float aj = __shfl(a_l, j);
            if (D == 128) {
                float2 v = unpack_h2(fp[(size_t)cj * 64 + lane]);
                acc0 = fmaf(aj, v.x, acc0);
                acc1 = fmaf(aj, v.y, acc1);
            } else {
                float2 v = unpack_h2(fp[(size_t)cj * 32 + (lane >> 1)]);
                acc0 = fmaf(aj, (lane & 1) ? v.y : v.x, acc0);
            }
        }
    } else if (len > 64) {
        const float sr = s[r];
        float m = -INFINITY;
        for (int j = start + lane; j < end; j += 64) {
            float e = sr + d[cs[j]];
            e = (e >= 0.f) ? e : NEG_SLOPE * e;
            m = fmaxf(m, e);
        }
#pragma unroll
        for (int off = 32; off >= 1; off >>= 1) m = fmaxf(m, __shfl_xor(m, off));
        float den = 0.f;
        for (int j = start + lane; j < end; j += 64) {
            float e = sr + d[cs[j]];
            e = (e >= 0.f) ? e : NEG_SLOPE * e;
            den += __expf(e - m);
        }
#pragma unroll
        for (int off = 32; off >= 1; off >>= 1) den += __shfl_xor(den, off);
        const float inv = 1.f / den;
        for (int j = start; j < end; ++j) {
            int c = __builtin_amdgcn_readfirstlane(cs[j]);
            float e = sr + d[c];
            e = (e >= 0.f) ? e : NEG_SLOPE * e;
            float alpha = __expf(e - m) * inv;
            if (D == 128) {
                float2 v = unpack_h2(fp[(size_t)c * 64 + lane]);
                acc0 = fmaf(alpha, v.x, acc0);
                acc1 = fmaf(alpha, v.y, acc1);
            } else {
                float2 v = unpack_h2(fp[(size_t)c * 32 + (lane >> 1)]);
                acc0 = fmaf(alpha, (lane & 1) ? v.y : v.x, acc0);
            }
        }
    }

    if (D == 128)
        *(float2*)&out[(size_t)r * D + 2 * lane] = make_float2(acc0, acc1);
    else
        out[(size_t)r * D + lane] = acc0;
}

extern "C" void kernel_launch(void* const* d_in, const int* in_sizes, int n_in,
                              void* d_out, int out_size, void* d_ws, size_t ws_size,
                              hipStream_t stream) {
    const float* x   = (const float*)d_in[0];
    const int*   edg = (const int*)d_in[1];
    const float* W1  = (const float*)d_in[2];
    const float* W2  = (const float*)d_in[3];
    const float* as1 = (const float*)d_in[4];
    const float* ad1 = (const float*)d_in[5];
    const float* as2 = (const float*)d_in[6];
    const float* ad2 = (const float*)d_in[7];

    const int N = in_sizes[0] / 256;
    const int E = in_sizes[1] / 2;
    const int* row = edg;
    const int* col = edg + E;
    const int NB = (N + 511) / 512;

    // Workspace layout
    char* p = (char*)d_ws;
    f16* h1f = (f16*)p;     p += (size_t)N * 128 * 2;   // layer-1 features, fp16
    f16* h2f = (f16*)p;     p += (size_t)N * 64 * 2;    // layer-2 features, fp16
    // staging (dead before g1 written) aliases g1
    char* g1s = p;
    float* g1 = (float*)g1s;
    uint2* staging = (uint2*)g1s;
    size_t g1_bytes = (size_t)N * 128 * 4;
    size_t stg_bytes = (size_t)NB * BKT_CAP * 8;
    p += (g1_bytes > stg_bytes) ? g1_bytes : stg_bytes;
    float* sm = (float*)p;  p += (size_t)N * 4 * 4;     // s1,d1,s2,d2
    float* s1 = sm + (size_t)N * 0;
    float* d1 = sm + (size_t)N * 1;
    float* s2 = sm + (size_t)N * 2;
    float* d2 = sm + (size_t)N * 3;
    f16* WH1 = (f16*)p;     p += (size_t)128 * 256 * 2; // W1 as fp16 [OUT][K]
    f16* WH2 = (f16*)p;     p += (size_t)64 * 128 * 2;  // W2 as fp16 [OUT][K]
    int* cnt = (int*)p;     p += (size_t)N * 4;         // row histogram (zeroed)
    int* gcnt = (int*)p;    p += 256 * 4;               // bucket cursors (zeroed)
    int* rp  = (int*)p;     p += (size_t)(N + 1) * 4;   // CSR row_ptr
    int* bsum = (int*)p;    p += 1024 * 4;
    int* boff = (int*)p;    p += 1024 * 4;
    int* cs  = (int*)p;     p += (size_t)E * 4;         // CSR col indices

    hipMemsetAsync(cnt, 0, ((size_t)N + 256) * 4, stream);  // cnt + gcnt

    convert_f16_kernel<<<(128 * 256 + 255) / 256, 256, 0, stream>>>(W1, WH1, 128 * 256);
    convert_f16_kernel<<<(64 * 128 + 255) / 256, 256, 0, stream>>>(W2, WH2, 64 * 128);

    const int EB = (E + 255) / 256;
    const int GB = (N + 127) / 128;
    const int SB = (N + 1023) / 1024;

    // CSR build: rp via verified hist+scan; cs via 2-level binned scatter
    hist_kernel<<<EB, 256, 0, stream>>>(row, cnt, E);
    scan1_kernel<<<SB, 1024, 0, stream>>>(cnt, rp, bsum, N);
    scan2_kernel<<<1, 64, 0, stream>>>(bsum, boff, SB);
    scan3_kernel<<<(N + 256) / 256, 256, 0, stream>>>(rp, boff, N, E);
    bin_kernel<<<(E + 4095) / 4096, 256, 0, stream>>>(row, col, gcnt, staging, E, NB);
    csr_scatter2<<<NB, 256, 0, stream>>>(staging, gcnt, rp, cs);

    // Layer 1
    gemm_mfma<256, 128, false><<<GB, 256, 0, stream>>>(x, WH1, as1, ad1, h1f, s1, d1, N);
    gat_csr_f16<128><<<(N + 3) / 4, 256, 0, stream>>>(rp, cs, s1, d1, (const u32*)h1f, g1, N);

    // Layer 2 (ELU fused into MFMA A-staging)
    gemm_mfma<128, 64, true><<<GB, 256, 0, stream>>>(g1, WH2, as2, ad2, h2f, s2, d2, N);
    gat_csr_f16<64><<<(N + 3) / 4, 256, 0, stream>>>(rp, cs, s2, d2, (const u32*)h2f,
                                                     (float*)d_out, N);
}

// Round 10
// 311.012 us; speedup vs baseline: 2.1749x; 1.0534x over previous
//
#include <hip/hip_runtime.h>
#include <hip/hip_fp16.h>
#include <math.h>

#define NEG_SLOPE 0.2f
typedef unsigned int u32;
typedef unsigned short u16;
typedef _Float16 f16;
typedef __attribute__((ext_vector_type(8))) _Float16 f16x8;
typedef __attribute__((ext_vector_type(4))) float f32x4;

__device__ __forceinline__ float2 unpack_h2(u32 v) {
    return __half22float2(*(const __half2*)&v);
}

// ---- one-time: build fragment-order fp16 B ----
// dst[((kb*NREP + j)*64 + lane)*8 + i] = W[j*16 + (lane&15)][kb*32 + (lane>>4)*8 + i]
template <int K, int OUT>
__global__ void build_bswz(const float* __restrict__ W, f16* __restrict__ dst) {
    constexpr int NREP = OUT / 16;
    constexpr int TOT = (K / 32) * NREP * 512;
    int idx = blockIdx.x * 256 + threadIdx.x;
    if (idx >= TOT) return;
    int i = idx & 7;
    int lane = (idx >> 3) & 63;
    int fj = (idx >> 9) % NREP;
    int kb = (idx >> 9) / NREP;
    int o = fj * 16 + (lane & 15);
    int k = kb * 32 + (lane >> 4) * 8 + i;
    dst[idx] = (f16)W[(size_t)o * K + k];
}

// ---- Single-stage MFMA fp16 GEMM: BM=64, whole A panel staged once ----
// Bswz is fragment-order fp16 (L1/L2-hot). Fused score dots; ELU on A optional.
template <int K, int OUT, bool ELU>
__global__ __launch_bounds__(256) void gemm_mfma(
        const float* __restrict__ A, const f16* __restrict__ Bswz,
        const float* __restrict__ asrc, const float* __restrict__ adst,
        f16* __restrict__ H, float* __restrict__ s_out, float* __restrict__ d_out_,
        int N) {
    constexpr int BM = 64;
    constexpr int LDA = K + 8;        // fp16 elems/row: 16B-aligned rows, cheap banks
    constexpr int NREP = OUT / 16;
    constexpr int KB = K / 32;
    __shared__ f16 As[BM * LDA];
    const int t = threadIdx.x;
    const int w = t >> 6, lane = t & 63;
    const int r16 = lane & 15, g = lane >> 4;
    const int n0 = blockIdx.x * BM;

    // stage whole A panel f32->fp16; all loads issued back-to-back (deep MLP)
    constexpr int F4PR = K / 4;       // float4 per row
#pragma unroll
    for (int it = 0; it < BM * F4PR / 256; ++it) {
        int q = t + 256 * it;
        int m = q / F4PR, c = q % F4PR;
        int gr = n0 + m;
        float4 v = make_float4(0.f, 0.f, 0.f, 0.f);
        if (gr < N) v = *(const float4*)&A[(size_t)gr * K + 4 * c];
        if (ELU) {
            v.x = v.x > 0.f ? v.x : expm1f(v.x);
            v.y = v.y > 0.f ? v.y : expm1f(v.y);
            v.z = v.z > 0.f ? v.z : expm1f(v.z);
            v.w = v.w > 0.f ? v.w : expm1f(v.w);
        }
        f16 tmp[4] = {(f16)v.x, (f16)v.y, (f16)v.z, (f16)v.w};
        *(uint2*)&As[m * LDA + 4 * c] = *(uint2*)tmp;
    }
    __syncthreads();   // the only barrier

    f32x4 acc[NREP];
#pragma unroll
    for (int j = 0; j < NREP; ++j) acc[j] = (f32x4){0.f, 0.f, 0.f, 0.f};

#pragma unroll
    for (int kb = 0; kb < KB; ++kb) {
        f16x8 afr = *(const f16x8*)&As[(w * 16 + r16) * LDA + kb * 32 + 8 * g];
#pragma unroll
        for (int j = 0; j < NREP; ++j) {
            f16x8 bfr = *(const f16x8*)&Bswz[(((kb * NREP) + j) << 9) + (lane << 3)];
            acc[j] = __builtin_amdgcn_mfma_f32_16x16x32_f16(afr, bfr, acc[j], 0, 0, 0);
        }
    }

    // epilogue: fp16 H + fused score dots. C/D: col=lane&15, row=(lane>>4)*4+reg.
#pragma unroll
    for (int reg = 0; reg < 4; ++reg) {
        int m = n0 + w * 16 + g * 4 + reg;
        float vs = 0.f, vd = 0.f;
        if (m < N) {
#pragma unroll
            for (int j = 0; j < NREP; ++j) {
                float val = acc[j][reg];
                H[(size_t)m * OUT + j * 16 + r16] = (f16)val;
                vs = fmaf(val, asrc[j * 16 + r16], vs);
                vd = fmaf(val, adst[j * 16 + r16], vd);
            }
        }
#pragma unroll
        for (int off = 8; off >= 1; off >>= 1) {
            vs += __shfl_down(vs, off, 16);
            vd += __shfl_down(vd, off, 16);
        }
        if (r16 == 0 && m < N) {
            s_out[m] = vs;
            d_out_[m] = vd;
        }
    }
}

// ---- CSR build: histogram -> scan (verified) ----
__global__ void hist_kernel(const int* __restrict__ row, int* __restrict__ cnt, int E) {
    int i = blockIdx.x * blockDim.x + threadIdx.x;
    if (i < E) atomicAdd(&cnt[row[i]], 1);
}

__global__ __launch_bounds__(1024) void scan1_kernel(const int* __restrict__ cnt,
                                                     int* __restrict__ exc,
                                                     int* __restrict__ bsum, int N) {
    __shared__ int s[1024];
    const int t = threadIdx.x;
    const int i = blockIdx.x * 1024 + t;
    int v = (i < N) ? cnt[i] : 0;
    s[t] = v;
    __syncthreads();
    for (int off = 1; off < 1024; off <<= 1) {
        int x = (t >= off) ? s[t - off] : 0;
        __syncthreads();
        s[t] += x;
        __syncthreads();
    }
    if (i < N) exc[i] = s[t] - v;
    if (t == 1023) bsum[blockIdx.x] = s[t];
}

__global__ void scan2_kernel(int* __restrict__ bsum, int* __restrict__ boff, int nb) {
    if (threadIdx.x == 0 && blockIdx.x == 0) {
        int acc = 0;
        for (int i = 0; i < nb; ++i) { boff[i] = acc; acc += bsum[i]; }
    }
}

__global__ void scan3_kernel(int* __restrict__ rp, const int* __restrict__ boff,
                             int N, int E) {
    int i = blockIdx.x * blockDim.x + threadIdx.x;
    if (i < N) rp[i] += boff[i >> 10];
    if (i == 0) rp[N] = E;
}

// ---- Pass A: bin edges by bucket (row>>9) with LDS staging, coalesced flush ----
#define BKT_CAP 12288
__global__ __launch_bounds__(256) void bin_kernel(
        const int* __restrict__ row, const int* __restrict__ col,
        int* __restrict__ gcnt, uint2* __restrict__ staging, int E, int NB) {
    __shared__ int hist[256];
    __shared__ int scn[256];
    __shared__ int start[256];
    __shared__ int cursor[256];
    __shared__ int gbase[256];
    __shared__ uint2 binned[4096];
    const int t = threadIdx.x;
    const int base = blockIdx.x * 4096;
    const int cnt = min(4096, E - base);

    hist[t] = 0;
    __syncthreads();

    int myr[16], myc[16];
#pragma unroll
    for (int it = 0; it < 16; ++it) {
        int q = t + 256 * it;
        if (q < cnt) {
            myr[it] = row[base + q];
            myc[it] = col[base + q];
            atomicAdd(&hist[myr[it] >> 9], 1);
        }
    }
    __syncthreads();

    int v = hist[t];
    scn[t] = v;
    __syncthreads();
    for (int off = 1; off < 256; off <<= 1) {
        int x = (t >= off) ? scn[t - off] : 0;
        __syncthreads();
        scn[t] += x;
        __syncthreads();
    }
    start[t] = scn[t] - v;
    cursor[t] = scn[t] - v;
    __syncthreads();

#pragma unroll
    for (int it = 0; it < 16; ++it) {
        int q = t + 256 * it;
        if (q < cnt) {
            int b = myr[it] >> 9;
            int slot = atomicAdd(&cursor[b], 1);
            binned[slot] = make_uint2((u32)myr[it], (u32)myc[it]);
        }
    }
    __syncthreads();

    if (t < NB && hist[t] > 0) gbase[t] = atomicAdd(&gcnt[t], hist[t]);
    __syncthreads();

    for (int q = t; q < cnt; q += 256) {
        uint2 e = binned[q];
        int b = (int)(e.x >> 9);
        int pos = gbase[b] + (q - start[b]);
        staging[(size_t)b * BKT_CAP + pos] = e;
    }
}

// ---- Pass B: one block per bucket; scatter into cs within a ~32KB window ----
__global__ __launch_bounds__(256) void csr_scatter2(
        const uint2* __restrict__ staging, const int* __restrict__ gcnt,
        const int* __restrict__ rp, int* __restrict__ cs) {
    __shared__ int cur[512];
    const int b = blockIdx.x;
    const int t = threadIdx.x;
    cur[t] = 0;
    cur[t + 256] = 0;
    __syncthreads();
    const int n = gcnt[b];
    for (int i = t; i < n; i += 256) {
        uint2 e = staging[(size_t)b * BKT_CAP + i];
        int p = rp[e.x] + atomicAdd(&cur[e.x & 511], 1);
        cs[p] = (int)e.y;
    }
}

// ---- Fused GAT layer over CSR, fp16 gather, shfl-broadcast phase 3 ----
template <int D>
__global__ __launch_bounds__(256) void gat_csr_f16(
        const int* __restrict__ rp, const int* __restrict__ cs,
        const float* __restrict__ s, const float* __restrict__ d,
        const u32* __restrict__ fp,  // packed fp16 pairs, row stride D/2
        float* __restrict__ out, int N) {
    const int wid = threadIdx.x >> 6;
    const int lane = threadIdx.x & 63;
    const int r = blockIdx.x * 4 + wid;
    if (r >= N) return;
    const int start = rp[r], end = rp[r + 1];
    const int len = end - start;

    float acc0 = 0.f, acc1 = 0.f;

    if (len > 0 && len <= 64) {
        const float sr = s[r];
        int c_l = 0;
        float e_l = -INFINITY;
        if (lane < len) {
            c_l = cs[start + lane];
            float e = sr + d[c_l];
            e_l = (e >= 0.f) ? e : NEG_SLOPE * e;
        }
        float m = e_l;
#pragma unroll
        for (int off = 32; off >= 1; off >>= 1) m = fmaxf(m, __shfl_xor(m, off));
        float ex_l = (lane < len) ? __expf(e_l - m) : 0.f;
        float den = ex_l;
#pragma unroll
        for (int off = 32; off >= 1; off >>= 1) den += __shfl_xor(den, off);
        const float a_l = ex_l * (1.f / den);

        int j = 0;
        for (; j + 4 <= len; j += 4) {
            int c0 = __shfl(c_l, j), c1 = __shfl(c_l, j + 1);
            int c2 = __shfl(c_l, j + 2), c3 = __shfl(c_l, j + 3);
            float a0 = __shfl(a_l, j), a1 = __shfl(a_l, j + 1);
            float a2 = __shfl(a_l, j + 2), a3 = __shfl(a_l, j + 3);
            if (D == 128) {
                u32 v0 = fp[(size_t)c0 * 64 + lane];
                u32 v1 = fp[(size_t)c1 * 64 + lane];
                u32 v2 = fp[(size_t)c2 * 64 + lane];
                u32 v3 = fp[(size_t)c3 * 64 + lane];
                float2 f0 = unpack_h2(v0), f1 = unpack_h2(v1);
                float2 f2 = unpack_h2(v2), f3 = unpack_h2(v3);
                acc0 = fmaf(a0, f0.x, acc0); acc1 = fmaf(a0, f0.y, acc1);
                acc0 = fmaf(a1, f1.x, acc0); acc1 = fmaf(a1, f1.y, acc1);
                acc0 = fmaf(a2, f2.x, acc0); acc1 = fmaf(a2, f2.y, acc1);
                acc0 = fmaf(a3, f3.x, acc0); acc1 = fmaf(a3, f3.y, acc1);
            } else {
                u32 v0 = fp[(size_t)c0 * 32 + (lane >> 1)];
                u32 v1 = fp[(size_t)c1 * 32 + (lane >> 1)];
                u32 v2 = fp[(size_t)c2 * 32 + (lane >> 1)];
                u32 v3 = fp[(size_t)c3 * 32 + (lane >> 1)];
                float2 f0 = unpack_h2(v0), f1 = unpack_h2(v1);
                float2 f2 = unpack_h2(v2), f3 = unpack_h2(v3);
                acc0 = fmaf(a0, (lane & 1) ? f0.y : f0.x, acc0);
                acc0 = fmaf(a1, (lane & 1) ? f1.y : f1.x, acc0);
                acc0 = fmaf(a2, (lane & 1) ? f2.y : f2.x, acc0);
                acc0 = fmaf(a3, (lane & 1) ? f3.y : f3.x, acc0);
            }
        }
        for (; j < len; ++j) {
            int cj = __shfl(c_l, j);
            float aj = __shfl(a_l, j);
            if (D == 128) {
                float2 v = unpack_h2(fp[(size_t)cj * 64 + lane]);
                acc0 = fmaf(aj, v.x, acc0);
                acc1 = fmaf(aj, v.y, acc1);
            } else {
                float2 v = unpack_h2(fp[(size_t)cj * 32 + (lane >> 1)]);
                acc0 = fmaf(aj, (lane & 1) ? v.y : v.x, acc0);
            }
        }
    } else if (len > 64) {
        const float sr = s[r];
        float m = -INFINITY;
        for (int j = start + lane; j < end; j += 64) {
            float e = sr + d[cs[j]];
            e = (e >= 0.f) ? e : NEG_SLOPE * e;
            m = fmaxf(m, e);
        }
#pragma unroll
        for (int off = 32; off >= 1; off >>= 1) m = fmaxf(m, __shfl_xor(m, off));
        float den = 0.f;
        for (int j = start + lane; j < end; j += 64) {
            float e = sr + d[cs[j]];
            e = (e >= 0.f) ? e : NEG_SLOPE * e;
            den += __expf(e - m);
        }
#pragma unroll
        for (int off = 32; off >= 1; off >>= 1) den += __shfl_xor(den, off);
        const float inv = 1.f / den;
        for (int j = start; j < end; ++j) {
            int c = __builtin_amdgcn_readfirstlane(cs[j]);
            float e = sr + d[c];
            e = (e >= 0.f) ? e : NEG_SLOPE * e;
            float alpha = __expf(e - m) * inv;
            if (D == 128) {
                float2 v = unpack_h2(fp[(size_t)c * 64 + lane]);
                acc0 = fmaf(alpha, v.x, acc0);
                acc1 = fmaf(alpha, v.y, acc1);
            } else {
                float2 v = unpack_h2(fp[(size_t)c * 32 + (lane >> 1)]);
                acc0 = fmaf(alpha, (lane & 1) ? v.y : v.x, acc0);
            }
        }
    }

    if (D == 128)
        *(float2*)&out[(size_t)r * D + 2 * lane] = make_float2(acc0, acc1);
    else
        out[(size_t)r * D + lane] = acc0;
}

extern "C" void kernel_launch(void* const* d_in, const int* in_sizes, int n_in,
                              void* d_out, int out_size, void* d_ws, size_t ws_size,
                              hipStream_t stream) {
    const float* x   = (const float*)d_in[0];
    const int*   edg = (const int*)d_in[1];
    const float* W1  = (const float*)d_in[2];
    const float* W2  = (const float*)d_in[3];
    const float* as1 = (const float*)d_in[4];
    const float* ad1 = (const float*)d_in[5];
    const float* as2 = (const float*)d_in[6];
    const float* ad2 = (const float*)d_in[7];

    const int N = in_sizes[0] / 256;
    const int E = in_sizes[1] / 2;
    const int* row = edg;
    const int* col = edg + E;
    const int NB = (N + 511) / 512;

    // Workspace layout
    char* p = (char*)d_ws;
    f16* h1f = (f16*)p;     p += (size_t)N * 128 * 2;   // layer-1 features, fp16
    f16* h2f = (f16*)p;     p += (size_t)N * 64 * 2;    // layer-2 features, fp16
    // staging (dead before g1 written) aliases g1
    char* g1s = p;
    float* g1 = (float*)g1s;
    uint2* staging = (uint2*)g1s;
    size_t g1_bytes = (size_t)N * 128 * 4;
    size_t stg_bytes = (size_t)NB * BKT_CAP * 8;
    p += (g1_bytes > stg_bytes) ? g1_bytes : stg_bytes;
    float* sm = (float*)p;  p += (size_t)N * 4 * 4;     // s1,d1,s2,d2
    float* s1 = sm + (size_t)N * 0;
    float* d1 = sm + (size_t)N * 1;
    float* s2 = sm + (size_t)N * 2;
    float* d2 = sm + (size_t)N * 3;
    f16* B1 = (f16*)p;      p += (size_t)128 * 256 * 2; // W1 fragment-order fp16
    f16* B2 = (f16*)p;      p += (size_t)64 * 128 * 2;  // W2 fragment-order fp16
    int* cnt = (int*)p;     p += (size_t)N * 4;         // row histogram (zeroed)
    int* gcnt = (int*)p;    p += 256 * 4;               // bucket cursors (zeroed)
    int* rp  = (int*)p;     p += (size_t)(N + 1) * 4;   // CSR row_ptr
    int* bsum = (int*)p;    p += 1024 * 4;
    int* boff = (int*)p;    p += 1024 * 4;
    int* cs  = (int*)p;     p += (size_t)E * 4;         // CSR col indices

    hipMemsetAsync(cnt, 0, ((size_t)N + 256) * 4, stream);  // cnt + gcnt

    build_bswz<256, 128><<<128, 256, 0, stream>>>(W1, B1);
    build_bswz<128, 64><<<32, 256, 0, stream>>>(W2, B2);

    const int EB = (E + 255) / 256;
    const int GB = (N + 63) / 64;
    const int SB = (N + 1023) / 1024;

    // CSR build: rp via verified hist+scan; cs via 2-level binned scatter
    hist_kernel<<<EB, 256, 0, stream>>>(row, cnt, E);
    scan1_kernel<<<SB, 1024, 0, stream>>>(cnt, rp, bsum, N);
    scan2_kernel<<<1, 64, 0, stream>>>(bsum, boff, SB);
    scan3_kernel<<<(N + 256) / 256, 256, 0, stream>>>(rp, boff, N, E);
    bin_kernel<<<(E + 4095) / 4096, 256, 0, stream>>>(row, col, gcnt, staging, E, NB);
    csr_scatter2<<<NB, 256, 0, stream>>>(staging, gcnt, rp, cs);

    // Layer 1
    gemm_mfma<256, 128, false><<<GB, 256, 0, stream>>>(x, B1, as1, ad1, h1f, s1, d1, N);
    gat_csr_f16<128><<<(N + 3) / 4, 256, 0, stream>>>(rp, cs, s1, d1, (const u32*)h1f, g1, N);

    // Layer 2 (ELU fused into MFMA A-staging)
    gemm_mfma<128, 64, true><<<GB, 256, 0, stream>>>(g1, B2, as2, ad2, h2f, s2, d2, N);
    gat_csr_f16<64><<<(N + 3) / 4, 256, 0, stream>>>(rp, cs, s2, d2, (const u32*)h2f,
                                                     (float*)d_out, N);
}

// Round 11
// 221.466 us; speedup vs baseline: 3.0544x; 1.4043x over previous
//
#include <hip/hip_runtime.h>
#include <hip/hip_fp16.h>
#include <math.h>

#define NEG_SLOPE 0.2f
typedef unsigned int u32;
typedef unsigned short u16;
typedef _Float16 f16;
typedef __attribute__((ext_vector_type(8))) _Float16 f16x8;
typedef __attribute__((ext_vector_type(4))) float f32x4;

__device__ __forceinline__ float2 unpack_h2(u32 v) {
    return __half22float2(*(const __half2*)&v);
}

// ---- one-time: build fragment-order fp16 B ----
template <int K, int OUT>
__global__ void build_bswz(const float* __restrict__ W, f16* __restrict__ dst) {
    constexpr int NREP = OUT / 16;
    constexpr int TOT = (K / 32) * NREP * 512;
    int idx = blockIdx.x * 256 + threadIdx.x;
    if (idx >= TOT) return;
    int i = idx & 7;
    int lane = (idx >> 3) & 63;
    int fj = (idx >> 9) % NREP;
    int kb = (idx >> 9) / NREP;
    int o = fj * 16 + (lane & 15);
    int k = kb * 32 + (lane >> 4) * 8 + i;
    dst[idx] = (f16)W[(size_t)o * K + k];
}

// ---- Single-stage MFMA fp16 GEMM: BM=64, whole A panel staged once ----
template <int K, int OUT, bool ELU, bool F16IN>
__global__ __launch_bounds__(256) void gemm_mfma(
        const void* __restrict__ Ap, const f16* __restrict__ Bswz,
        const float* __restrict__ asrc, const float* __restrict__ adst,
        f16* __restrict__ H, float* __restrict__ s_out, float* __restrict__ d_out_,
        int N) {
    constexpr int BM = 64;
    constexpr int LDA = K + 8;
    constexpr int NREP = OUT / 16;
    constexpr int KB = K / 32;
    __shared__ f16 As[BM * LDA];
    const int t = threadIdx.x;
    const int w = t >> 6, lane = t & 63;
    const int r16 = lane & 15, g = lane >> 4;
    const int n0 = blockIdx.x * BM;

    constexpr int F4PR = K / 4;  // 4-elem groups per row
#pragma unroll
    for (int it = 0; it < BM * F4PR / 256; ++it) {
        int q = t + 256 * it;
        int m = q / F4PR, c = q % F4PR;
        int gr = n0 + m;
        float vx = 0.f, vy = 0.f, vz = 0.f, vw = 0.f;
        if (gr < N) {
            if (F16IN) {
                const f16* Af = (const f16*)Ap;
                uint2 raw = *(const uint2*)&Af[(size_t)gr * K + 4 * c];
                float2 lo = unpack_h2(raw.x), hi = unpack_h2(raw.y);
                vx = lo.x; vy = lo.y; vz = hi.x; vw = hi.y;
            } else {
                float4 v = *(const float4*)&((const float*)Ap)[(size_t)gr * K + 4 * c];
                vx = v.x; vy = v.y; vz = v.z; vw = v.w;
            }
        }
        if (ELU) {
            vx = vx > 0.f ? vx : expm1f(vx);
            vy = vy > 0.f ? vy : expm1f(vy);
            vz = vz > 0.f ? vz : expm1f(vz);
            vw = vw > 0.f ? vw : expm1f(vw);
        }
        f16 tmp[4] = {(f16)vx, (f16)vy, (f16)vz, (f16)vw};
        *(uint2*)&As[m * LDA + 4 * c] = *(uint2*)tmp;
    }
    __syncthreads();   // the only barrier

    f32x4 acc[NREP];
#pragma unroll
    for (int j = 0; j < NREP; ++j) acc[j] = (f32x4){0.f, 0.f, 0.f, 0.f};

#pragma unroll
    for (int kb = 0; kb < KB; ++kb) {
        f16x8 afr = *(const f16x8*)&As[(w * 16 + r16) * LDA + kb * 32 + 8 * g];
#pragma unroll
        for (int j = 0; j < NREP; ++j) {
            f16x8 bfr = *(const f16x8*)&Bswz[(((kb * NREP) + j) << 9) + (lane << 3)];
            acc[j] = __builtin_amdgcn_mfma_f32_16x16x32_f16(afr, bfr, acc[j], 0, 0, 0);
        }
    }

    // epilogue: fp16 H + fused score dots. C/D: col=lane&15, row=(lane>>4)*4+reg.
#pragma unroll
    for (int reg = 0; reg < 4; ++reg) {
        int m = n0 + w * 16 + g * 4 + reg;
        float vs = 0.f, vd = 0.f;
        if (m < N) {
#pragma unroll
            for (int j = 0; j < NREP; ++j) {
                float val = acc[j][reg];
                H[(size_t)m * OUT + j * 16 + r16] = (f16)val;
                vs = fmaf(val, asrc[j * 16 + r16], vs);
                vd = fmaf(val, adst[j * 16 + r16], vd);
            }
        }
#pragma unroll
        for (int off = 8; off >= 1; off >>= 1) {
            vs += __shfl_down(vs, off, 16);
            vd += __shfl_down(vd, off, 16);
        }
        if (r16 == 0 && m < N) {
            s_out[m] = vs;
            d_out_[m] = vd;
        }
    }
}

// ---- Pass A: bin edges by bucket (row>>9) with LDS staging, coalesced flush ----
#define BKT_CAP 12288
__global__ __launch_bounds__(256) void bin_kernel(
        const int* __restrict__ row, const int* __restrict__ col,
        int* __restrict__ gcnt, uint2* __restrict__ staging, int E, int NB) {
    __shared__ int hist[256];
    __shared__ int scn[256];
    __shared__ int start[256];
    __shared__ int cursor[256];
    __shared__ int gbase[256];
    __shared__ uint2 binned[4096];
    const int t = threadIdx.x;
    const int base = blockIdx.x * 4096;
    const int cnt = min(4096, E - base);

    hist[t] = 0;
    __syncthreads();

    int myr[16], myc[16];
#pragma unroll
    for (int it = 0; it < 16; ++it) {
        int q = t + 256 * it;
        if (q < cnt) {
            myr[it] = row[base + q];
            myc[it] = col[base + q];
            atomicAdd(&hist[myr[it] >> 9], 1);
        }
    }
    __syncthreads();

    int v = hist[t];
    scn[t] = v;
    __syncthreads();
    for (int off = 1; off < 256; off <<= 1) {
        int x = (t >= off) ? scn[t - off] : 0;
        __syncthreads();
        scn[t] += x;
        __syncthreads();
    }
    start[t] = scn[t] - v;
    cursor[t] = scn[t] - v;
    __syncthreads();

#pragma unroll
    for (int it = 0; it < 16; ++it) {
        int q = t + 256 * it;
        if (q < cnt) {
            int b = myr[it] >> 9;
            int slot = atomicAdd(&cursor[b], 1);
            binned[slot] = make_uint2((u32)myr[it], (u32)myc[it]);
        }
    }
    __syncthreads();

    if (t < NB && hist[t] > 0) gbase[t] = atomicAdd(&gcnt[t], hist[t]);
    __syncthreads();

    for (int q = t; q < cnt; q += 256) {
        uint2 e = binned[q];
        int b = (int)(e.x >> 9);
        int pos = gbase[b] + (q - start[b]);
        staging[(size_t)b * BKT_CAP + pos] = e;
    }
}

// ---- tiny: exclusive scan of per-bucket counts (NB <= 256, one block) ----
__global__ __launch_bounds__(256) void scan_gcnt(const int* __restrict__ gcnt,
                                                 int* __restrict__ gbase, int NB) {
    __shared__ int s[256];
    const int t = threadIdx.x;
    int v = (t < NB) ? gcnt[t] : 0;
    s[t] = v;
    __syncthreads();
    for (int off = 1; off < 256; off <<= 1) {
        int x = (t >= off) ? s[t - off] : 0;
        __syncthreads();
        s[t] += x;
        __syncthreads();
    }
    gbase[t] = s[t] - v;
}

// ---- Pass B: per bucket, build rp (LDS hist+scan over 512 rows) and scatter cs ----
__global__ __launch_bounds__(256) void csr_scatter2(
        const uint2* __restrict__ staging, const int* __restrict__ gcnt,
        const int* __restrict__ gbase, int* __restrict__ rp, int* __restrict__ cs,
        int N) {
    __shared__ int cnt[512];
    __shared__ int exc[512];
    const int b = blockIdx.x;
    const int t = threadIdx.x;
    cnt[t] = 0;
    cnt[t + 256] = 0;
    __syncthreads();
    const int n = gcnt[b];
    const int base = gbase[b];
    const size_t sb = (size_t)b * BKT_CAP;

    for (int i = t; i < n; i += 256)
        atomicAdd(&cnt[staging[sb + i].x & 511], 1);
    __syncthreads();

    // 512-entry Hillis-Steele inclusive scan, 2 elems/thread
    int v0 = cnt[t], v1 = cnt[t + 256];
    exc[t] = v0;
    exc[t + 256] = v1;
    __syncthreads();
    for (int off = 1; off < 512; off <<= 1) {
        int x0 = (t >= off) ? exc[t - off] : 0;
        int x1 = exc[t + 256 - off];
        __syncthreads();
        exc[t] += x0;
        exc[t + 256] += x1;
        __syncthreads();
    }
    int e0 = exc[t] - v0, e1 = exc[t + 256] - v1;
    int r0 = (b << 9) + t, r1 = (b << 9) + t + 256;
    if (r0 <= N) rp[r0] = base + e0;
    if (r1 <= N) rp[r1] = base + e1;
    // reuse exc[] as cursors
    exc[t] = e0;
    exc[t + 256] = e1;
    __syncthreads();

    for (int i = t; i < n; i += 256) {
        uint2 e = staging[sb + i];
        int p = base + atomicAdd(&exc[e.x & 511], 1);
        cs[p] = (int)e.y;
    }
}

// ---- Fused GAT layer over CSR: NSUB sub-groups gather NSUB edges per step ----
template <int D, bool OUTF32>
__global__ __launch_bounds__(256) void gat_csr_f16(
        const int* __restrict__ rp, const int* __restrict__ cs,
        const float* __restrict__ s, const float* __restrict__ d,
        const u32* __restrict__ fp,  // fp16 features, row = D/4 uint2
        void* __restrict__ outp, int N) {
    constexpr int G = D / 4;      // lanes per edge (32 for D=128, 16 for D=64)
    constexpr int NSUB = 64 / G;  // edges per step
    const int wid = threadIdx.x >> 6;
    const int lane = threadIdx.x & 63;
    const int li = lane & (G - 1);
    const int sub = lane / G;
    const int r = blockIdx.x * 4 + wid;
    if (r >= N) return;
    const int start = rp[r], end = rp[r + 1];
    const int len = end - start;
    const uint2* fp2 = (const uint2*)fp;

    float4 acc = make_float4(0.f, 0.f, 0.f, 0.f);

    if (len > 0 && len <= 64) {
        const float sr = s[r];
        // per-lane edge data (verified masked-lane softmax)
        int c_l = 0;
        float e_l = -INFINITY;
        if (lane < len) {
            c_l = cs[start + lane];
            float e = sr + d[c_l];
            e_l = (e >= 0.f) ? e : NEG_SLOPE * e;
        }
        float m = e_l;
#pragma unroll
        for (int off = 32; off >= 1; off >>= 1) m = fmaxf(m, __shfl_xor(m, off));
        float ex_l = (lane < len) ? __expf(e_l - m) : 0.f;
        float den = ex_l;
#pragma unroll
        for (int off = 32; off >= 1; off >>= 1) den += __shfl_xor(den, off);
        const float a_l = ex_l * (1.f / den);

        // 2*NSUB edges per iteration; idle lanes have a=0, c=0 (harmless load)
        for (int j = 0; j < len; j += 2 * NSUB) {
            int i0 = j + sub, i1 = j + NSUB + sub;  // < 64 always (step | 64)
            int c0 = __shfl(c_l, i0);
            int c1 = __shfl(c_l, i1);
            float a0 = __shfl(a_l, i0);
            float a1 = __shfl(a_l, i1);
            uint2 v0 = fp2[(size_t)c0 * G + li];
            uint2 v1 = fp2[(size_t)c1 * G + li];
            float2 p0 = unpack_h2(v0.x), q0 = unpack_h2(v0.y);
            acc.x = fmaf(a0, p0.x, acc.x);
            acc.y = fmaf(a0, p0.y, acc.y);
            acc.z = fmaf(a0, q0.x, acc.z);
            acc.w = fmaf(a0, q0.y, acc.w);
            float2 p1 = unpack_h2(v1.x), q1 = unpack_h2(v1.y);
            acc.x = fmaf(a1, p1.x, acc.x);
            acc.y = fmaf(a1, p1.y, acc.y);
            acc.z = fmaf(a1, q1.x, acc.z);
            acc.w = fmaf(a1, q1.y, acc.w);
        }
    } else if (len > 64) {
        // rare long-row fallback: serial edges, sub 0 accumulates
        const float sr = s[r];
        float m = -INFINITY;
        for (int j = start + lane; j < end; j += 64) {
            float e = sr + d[cs[j]];
            e = (e >= 0.f) ? e : NEG_SLOPE * e;
            m = fmaxf(m, e);
        }
#pragma unroll
        for (int off = 32; off >= 1; off >>= 1) m = fmaxf(m, __shfl_xor(m, off));
        float den = 0.f;
        for (int j = start + lane; j < end; j += 64) {
            float e = sr + d[cs[j]];
            e = (e >= 0.f) ? e : NEG_SLOPE * e;
            den += __expf(e - m);
        }
#pragma unroll
        for (int off = 32; off >= 1; off >>= 1) den += __shfl_xor(den, off);
        const float inv = 1.f / den;
        for (int j = start; j < end; ++j) {
            int c = __builtin_amdgcn_readfirstlane(cs[j]);
            float e = sr + d[c];
            e = (e >= 0.f) ? e : NEG_SLOPE * e;
            float alpha = __expf(e - m) * inv;
            if (sub == 0) {
                uint2 v = fp2[(size_t)c * G + li];
                float2 p = unpack_h2(v.x), q = unpack_h2(v.y);
                acc.x = fmaf(alpha, p.x, acc.x);
                acc.y = fmaf(alpha, p.y, acc.y);
                acc.z = fmaf(alpha, q.x, acc.z);
                acc.w = fmaf(alpha, q.y, acc.w);
            }
        }
    }

    // reduce across sub-groups
    if (NSUB == 4) {
        acc.x += __shfl_xor(acc.x, 16);
        acc.y += __shfl_xor(acc.y, 16);
        acc.z += __shfl_xor(acc.z, 16);
        acc.w += __shfl_xor(acc.w, 16);
    }
    if (NSUB >= 2) {
        acc.x += __shfl_xor(acc.x, 32);
        acc.y += __shfl_xor(acc.y, 32);
        acc.z += __shfl_xor(acc.z, 32);
        acc.w += __shfl_xor(acc.w, 32);
    }

    if (sub == 0) {
        if (OUTF32) {
            *(float4*)&((float*)outp)[(size_t)r * D + 4 * li] = acc;
        } else {
            __half2 h0 = __floats2half2_rn(acc.x, acc.y);
            __half2 h1 = __floats2half2_rn(acc.z, acc.w);
            uint2 pk = make_uint2(*(u32*)&h0, *(u32*)&h1);
            *(uint2*)&((f16*)outp)[(size_t)r * D + 4 * li] = pk;
        }
    }
}

extern "C" void kernel_launch(void* const* d_in, const int* in_sizes, int n_in,
                              void* d_out, int out_size, void* d_ws, size_t ws_size,
                              hipStream_t stream) {
    const float* x   = (const float*)d_in[0];
    const int*   edg = (const int*)d_in[1];
    const float* W1  = (const float*)d_in[2];
    const float* W2  = (const float*)d_in[3];
    const float* as1 = (const float*)d_in[4];
    const float* ad1 = (const float*)d_in[5];
    const float* as2 = (const float*)d_in[6];
    const float* ad2 = (const float*)d_in[7];

    const int N = in_sizes[0] / 256;
    const int E = in_sizes[1] / 2;
    const int* row = edg;
    const int* col = edg + E;
    const int NB = (N + 511) / 512;

    // Workspace layout
    char* p = (char*)d_ws;
    f16* h1f = (f16*)p;     p += (size_t)N * 128 * 2;   // layer-1 features, fp16
    f16* h2f = (f16*)p;     p += (size_t)N * 64 * 2;    // layer-2 features, fp16
    // staging (dead before g1 written) aliases g1 (now fp16)
    char* g1s = p;
    f16* g1h = (f16*)g1s;
    uint2* staging = (uint2*)g1s;
    size_t g1_bytes = (size_t)N * 128 * 2;
    size_t stg_bytes = (size_t)NB * BKT_CAP * 8;
    p += (g1_bytes > stg_bytes) ? g1_bytes : stg_bytes;
    float* sm = (float*)p;  p += (size_t)N * 4 * 4;     // s1,d1,s2,d2
    float* s1 = sm + (size_t)N * 0;
    float* d1 = sm + (size_t)N * 1;
    float* s2 = sm + (size_t)N * 2;
    float* d2 = sm + (size_t)N * 3;
    f16* B1 = (f16*)p;      p += (size_t)128 * 256 * 2; // W1 fragment-order fp16
    f16* B2 = (f16*)p;      p += (size_t)64 * 128 * 2;  // W2 fragment-order fp16
    int* gcnt = (int*)p;    p += 256 * 4;               // bucket counts (zeroed)
    int* gbase = (int*)p;   p += 256 * 4;               // bucket bases
    int* rp  = (int*)p;     p += (size_t)(N + 1) * 4;   // CSR row_ptr
    int* cs  = (int*)p;     p += (size_t)E * 4;         // CSR col indices

    hipMemsetAsync(gcnt, 0, 256 * 4, stream);

    build_bswz<256, 128><<<128, 256, 0, stream>>>(W1, B1);
    build_bswz<128, 64><<<32, 256, 0, stream>>>(W2, B2);

    const int GB = (N + 63) / 64;

    // CSR build: bin -> bucket scan -> per-bucket rp build + scatter
    bin_kernel<<<(E + 4095) / 4096, 256, 0, stream>>>(row, col, gcnt, staging, E, NB);
    scan_gcnt<<<1, 256, 0, stream>>>(gcnt, gbase, NB);
    csr_scatter2<<<NB, 256, 0, stream>>>(staging, gcnt, gbase, rp, cs, N);

    // Layer 1
    gemm_mfma<256, 128, false, false><<<GB, 256, 0, stream>>>(x, B1, as1, ad1, h1f, s1, d1, N);
    gat_csr_f16<128, false><<<(N + 3) / 4, 256, 0, stream>>>(rp, cs, s1, d1, (const u32*)h1f,
                                                             g1h, N);

    // Layer 2 (fp16 g1 in, ELU fused into MFMA A-staging)
    gemm_mfma<128, 64, true, true><<<GB, 256, 0, stream>>>(g1h, B2, as2, ad2, h2f, s2, d2, N);
    gat_csr_f16<64, true><<<(N + 3) / 4, 256, 0, stream>>>(rp, cs, s2, d2, (const u32*)h2f,
                                                           d_out, N);
}

// Round 12
// 218.508 us; speedup vs baseline: 3.0957x; 1.0135x over previous
//
#include <hip/hip_runtime.h>
#include <hip/hip_fp16.h>
#include <math.h>

#define NEG_SLOPE 0.2f
typedef unsigned int u32;
typedef unsigned short u16;
typedef _Float16 f16;
typedef __attribute__((ext_vector_type(8))) _Float16 f16x8;
typedef __attribute__((ext_vector_type(4))) float f32x4;

__device__ __forceinline__ float2 unpack_h2(u32 v) {
    return __half22float2(*(const __half2*)&v);
}

// ---- one-time: build fragment-order fp16 B for both weight matrices ----
__global__ void build_bswz_both(const float* __restrict__ W1, f16* __restrict__ B1,
                                const float* __restrict__ W2, f16* __restrict__ B2) {
    int idx = blockIdx.x * 256 + threadIdx.x;
    if (idx < 32768) {  // W1: K=256, OUT=128, NREP=8
        int i = idx & 7, lane = (idx >> 3) & 63, fj = (idx >> 9) & 7, kb = idx >> 12;
        int o = fj * 16 + (lane & 15), k = kb * 32 + (lane >> 4) * 8 + i;
        B1[idx] = (f16)W1[o * 256 + k];
    } else {
        int j = idx - 32768;  // W2: K=128, OUT=64, NREP=4
        if (j < 8192) {
            int i = j & 7, lane = (j >> 3) & 63, fj = (j >> 9) & 3, kb = j >> 11;
            int o = fj * 16 + (lane & 15), k = kb * 32 + (lane >> 4) * 8 + i;
            B2[j] = (f16)W2[o * 128 + k];
        }
    }
}

// ---- Single-stage MFMA fp16 GEMM: BM=64, whole A panel staged once ----
template <int K, int OUT, bool ELU, bool F16IN>
__global__ __launch_bounds__(256) void gemm_mfma(
        const void* __restrict__ Ap, const f16* __restrict__ Bswz,
        const float* __restrict__ asrc, const float* __restrict__ adst,
        f16* __restrict__ H, float* __restrict__ s_out, float* __restrict__ d_out_,
        int N) {
    constexpr int BM = 64;
    constexpr int LDA = K + 8;
    constexpr int NREP = OUT / 16;
    constexpr int KB = K / 32;
    __shared__ f16 As[BM * LDA];
    const int t = threadIdx.x;
    const int w = t >> 6, lane = t & 63;
    const int r16 = lane & 15, g = lane >> 4;
    const int n0 = blockIdx.x * BM;

    constexpr int F4PR = K / 4;
#pragma unroll
    for (int it = 0; it < BM * F4PR / 256; ++it) {
        int q = t + 256 * it;
        int m = q / F4PR, c = q % F4PR;
        int gr = n0 + m;
        float vx = 0.f, vy = 0.f, vz = 0.f, vw = 0.f;
        if (gr < N) {
            if (F16IN) {
                const f16* Af = (const f16*)Ap;
                uint2 raw = *(const uint2*)&Af[(size_t)gr * K + 4 * c];
                float2 lo = unpack_h2(raw.x), hi = unpack_h2(raw.y);
                vx = lo.x; vy = lo.y; vz = hi.x; vw = hi.y;
            } else {
                float4 v = *(const float4*)&((const float*)Ap)[(size_t)gr * K + 4 * c];
                vx = v.x; vy = v.y; vz = v.z; vw = v.w;
            }
        }
        if (ELU) {
            vx = vx > 0.f ? vx : expm1f(vx);
            vy = vy > 0.f ? vy : expm1f(vy);
            vz = vz > 0.f ? vz : expm1f(vz);
            vw = vw > 0.f ? vw : expm1f(vw);
        }
        f16 tmp[4] = {(f16)vx, (f16)vy, (f16)vz, (f16)vw};
        *(uint2*)&As[m * LDA + 4 * c] = *(uint2*)tmp;
    }
    __syncthreads();   // the only barrier

    f32x4 acc[NREP];
#pragma unroll
    for (int j = 0; j < NREP; ++j) acc[j] = (f32x4){0.f, 0.f, 0.f, 0.f};

#pragma unroll
    for (int kb = 0; kb < KB; ++kb) {
        f16x8 afr = *(const f16x8*)&As[(w * 16 + r16) * LDA + kb * 32 + 8 * g];
#pragma unroll
        for (int j = 0; j < NREP; ++j) {
            f16x8 bfr = *(const f16x8*)&Bswz[(((kb * NREP) + j) << 9) + (lane << 3)];
            acc[j] = __builtin_amdgcn_mfma_f32_16x16x32_f16(afr, bfr, acc[j], 0, 0, 0);
        }
    }

    // epilogue: fp16 H + fused score dots. C/D: col=lane&15, row=(lane>>4)*4+reg.
#pragma unroll
    for (int reg = 0; reg < 4; ++reg) {
        int m = n0 + w * 16 + g * 4 + reg;
        float vs = 0.f, vd = 0.f;
        if (m < N) {
#pragma unroll
            for (int j = 0; j < NREP; ++j) {
                float val = acc[j][reg];
                H[(size_t)m * OUT + j * 16 + r16] = (f16)val;
                vs = fmaf(val, asrc[j * 16 + r16], vs);
                vd = fmaf(val, adst[j * 16 + r16], vd);
            }
        }
#pragma unroll
        for (int off = 8; off >= 1; off >>= 1) {
            vs += __shfl_down(vs, off, 16);
            vd += __shfl_down(vd, off, 16);
        }
        if (r16 == 0 && m < N) {
            s_out[m] = vs;
            d_out_[m] = vd;
        }
    }
}

// ---- Pass A: bin edges by bucket (row>>9) with LDS staging, coalesced flush ----
#define BKT_CAP 12288
__global__ __launch_bounds__(256) void bin_kernel(
        const int* __restrict__ row, const int* __restrict__ col,
        int* __restrict__ gcnt, uint2* __restrict__ staging, int E, int NB) {
    __shared__ int hist[256];
    __shared__ int scn[256];
    __shared__ int start[256];
    __shared__ int cursor[256];
    __shared__ int gbase[256];
    __shared__ uint2 binned[4096];
    const int t = threadIdx.x;
    const int base = blockIdx.x * 4096;
    const int cnt = min(4096, E - base);

    hist[t] = 0;
    __syncthreads();

    int myr[16], myc[16];
#pragma unroll
    for (int it = 0; it < 16; ++it) {
        int q = t + 256 * it;
        if (q < cnt) {
            myr[it] = row[base + q];
            myc[it] = col[base + q];
            atomicAdd(&hist[myr[it] >> 9], 1);
        }
    }
    __syncthreads();

    int v = hist[t];
    scn[t] = v;
    __syncthreads();
    for (int off = 1; off < 256; off <<= 1) {
        int x = (t >= off) ? scn[t - off] : 0;
        __syncthreads();
        scn[t] += x;
        __syncthreads();
    }
    start[t] = scn[t] - v;
    cursor[t] = scn[t] - v;
    __syncthreads();

#pragma unroll
    for (int it = 0; it < 16; ++it) {
        int q = t + 256 * it;
        if (q < cnt) {
            int b = myr[it] >> 9;
            int slot = atomicAdd(&cursor[b], 1);
            binned[slot] = make_uint2((u32)myr[it], (u32)myc[it]);
        }
    }
    __syncthreads();

    if (t < NB && hist[t] > 0) gbase[t] = atomicAdd(&gcnt[t], hist[t]);
    __syncthreads();

    for (int q = t; q < cnt; q += 256) {
        uint2 e = binned[q];
        int b = (int)(e.x >> 9);
        int pos = gbase[b] + (q - start[b]);
        staging[(size_t)b * BKT_CAP + pos] = e;
    }
}

// ---- Pass B: per bucket, scan gcnt in-LDS, build rp, scatter cs ----
__global__ __launch_bounds__(256) void csr_scatter2(
        const uint2* __restrict__ staging, const int* __restrict__ gcnt,
        int* __restrict__ rp, int* __restrict__ cs, int N) {
    __shared__ int gsc[256];
    __shared__ int cnt[512];
    __shared__ int exc[512];
    const int b = blockIdx.x;
    const int t = threadIdx.x;

    // inclusive scan of the 256-entry bucket-count array (zero-padded by memset)
    int gv = gcnt[t];
    gsc[t] = gv;
    cnt[t] = 0;
    cnt[t + 256] = 0;
    __syncthreads();
    for (int off = 1; off < 256; off <<= 1) {
        int x = (t >= off) ? gsc[t - off] : 0;
        __syncthreads();
        gsc[t] += x;
        __syncthreads();
    }
    const int n = gcnt[b];
    const int base = gsc[b] - n;   // exclusive prefix
    const size_t sb = (size_t)b * BKT_CAP;

    for (int i = t; i < n; i += 256)
        atomicAdd(&cnt[staging[sb + i].x & 511], 1);
    __syncthreads();

    // 512-entry Hillis-Steele inclusive scan, 2 elems/thread
    int v0 = cnt[t], v1 = cnt[t + 256];
    exc[t] = v0;
    exc[t + 256] = v1;
    __syncthreads();
    for (int off = 1; off < 512; off <<= 1) {
        int x0 = (t >= off) ? exc[t - off] : 0;
        int x1 = exc[t + 256 - off];
        __syncthreads();
        exc[t] += x0;
        exc[t + 256] += x1;
        __syncthreads();
    }
    int e0 = exc[t] - v0, e1 = exc[t + 256] - v1;
    int r0 = (b << 9) + t, r1 = (b << 9) + t + 256;
    if (r0 <= N) rp[r0] = base + e0;
    if (r1 <= N) rp[r1] = base + e1;
    exc[t] = e0;
    exc[t + 256] = e1;
    __syncthreads();

    for (int i = t; i < n; i += 256) {
        uint2 e = staging[sb + i];
        int p = base + atomicAdd(&exc[e.x & 511], 1);
        cs[p] = (int)e.y;
    }
}

// ---- Fused GAT layer over CSR: sub-wave gather + packed-fp16 accumulate ----
template <int D, bool OUTF32>
__global__ __launch_bounds__(256) void gat_csr_f16(
        const int* __restrict__ rp, const int* __restrict__ cs,
        const float* __restrict__ s, const float* __restrict__ d,
        const u32* __restrict__ fp,  // fp16 features, row = D/4 uint2
        void* __restrict__ outp, int N) {
    constexpr int G = D / 4;      // lanes per edge
    constexpr int NSUB = 64 / G;  // edges per step
    const int wid = threadIdx.x >> 6;
    const int lane = threadIdx.x & 63;
    const int li = lane & (G - 1);
    const int sub = lane / G;
    const int r = blockIdx.x * 4 + wid;
    if (r >= N) return;
    const int start = rp[r], end = rp[r + 1];
    const int len = end - start;
    const uint2* fp2 = (const uint2*)fp;

    float4 acc = make_float4(0.f, 0.f, 0.f, 0.f);

    if (len > 0 && len <= 64) {
        const float sr = s[r];
        // per-lane edge data (verified masked-lane softmax)
        int c_l = 0;
        float e_l = -INFINITY;
        if (lane < len) {
            c_l = cs[start + lane];
            float e = sr + d[c_l];
            e_l = (e >= 0.f) ? e : NEG_SLOPE * e;
        }
        float m = e_l;
#pragma unroll
        for (int off = 32; off >= 1; off >>= 1) m = fmaxf(m, __shfl_xor(m, off));
        float ex_l = (lane < len) ? __expf(e_l - m) : 0.f;
        float den = ex_l;
#pragma unroll
        for (int off = 32; off >= 1; off >>= 1) den += __shfl_xor(den, off);
        const float a_l = ex_l * (1.f / den);

        // packed-fp16 accumulation: 2 pk_fma per edge per lane
        __half2 acch0 = __float2half2_rn(0.f), acch1 = acch0;
        for (int j = 0; j < len; j += 2 * NSUB) {
            int i0 = j + sub, i1 = j + NSUB + sub;  // always < 64
            int c0 = __shfl(c_l, i0);
            int c1 = __shfl(c_l, i1);
            float a0 = __shfl(a_l, i0);
            float a1 = __shfl(a_l, i1);
            uint2 v0 = fp2[(size_t)c0 * G + li];
            uint2 v1 = fp2[(size_t)c1 * G + li];
            __half2 a02 = __half2half2(__float2half(a0));
            __half2 a12 = __half2half2(__float2half(a1));
            acch0 = __hfma2(a02, *(const __half2*)&v0.x, acch0);
            acch1 = __hfma2(a02, *(const __half2*)&v0.y, acch1);
            acch0 = __hfma2(a12, *(const __half2*)&v1.x, acch0);
            acch1 = __hfma2(a12, *(const __half2*)&v1.y, acch1);
        }
        float2 lo = __half22float2(acch0), hi = __half22float2(acch1);
        acc = make_float4(lo.x, lo.y, hi.x, hi.y);
    } else if (len > 64) {
        // rare long-row fallback: serial edges, f32 accumulate, sub 0 only
        const float sr = s[r];
        float m = -INFINITY;
        for (int j = start + lane; j < end; j += 64) {
            float e = sr + d[cs[j]];
            e = (e >= 0.f) ? e : NEG_SLOPE * e;
            m = fmaxf(m, e);
        }
#pragma unroll
        for (int off = 32; off >= 1; off >>= 1) m = fmaxf(m, __shfl_xor(m, off));
        float den = 0.f;
        for (int j = start + lane; j < end; j += 64) {
            float e = sr + d[cs[j]];
            e = (e >= 0.f) ? e : NEG_SLOPE * e;
            den += __expf(e - m);
        }
#pragma unroll
        for (int off = 32; off >= 1; off >>= 1) den += __shfl_xor(den, off);
        const float inv = 1.f / den;
        for (int j = start; j < end; ++j) {
            int c = __builtin_amdgcn_readfirstlane(cs[j]);
            float e = sr + d[c];
            e = (e >= 0.f) ? e : NEG_SLOPE * e;
            float alpha = __expf(e - m) * inv;
            if (sub == 0) {
                uint2 v = fp2[(size_t)c * G + li];
                float2 p = unpack_h2(v.x), q = unpack_h2(v.y);
                acc.x = fmaf(alpha, p.x, acc.x);
                acc.y = fmaf(alpha, p.y, acc.y);
                acc.z = fmaf(alpha, q.x, acc.z);
                acc.w = fmaf(alpha, q.y, acc.w);
            }
        }
    }

    // reduce across sub-groups (f32)
    if (NSUB == 4) {
        acc.x += __shfl_xor(acc.x, 16);
        acc.y += __shfl_xor(acc.y, 16);
        acc.z += __shfl_xor(acc.z, 16);
        acc.w += __shfl_xor(acc.w, 16);
    }
    if (NSUB >= 2) {
        acc.x += __shfl_xor(acc.x, 32);
        acc.y += __shfl_xor(acc.y, 32);
        acc.z += __shfl_xor(acc.z, 32);
        acc.w += __shfl_xor(acc.w, 32);
    }

    if (sub == 0) {
        if (OUTF32) {
            *(float4*)&((float*)outp)[(size_t)r * D + 4 * li] = acc;
        } else {
            __half2 h0 = __floats2half2_rn(acc.x, acc.y);
            __half2 h1 = __floats2half2_rn(acc.z, acc.w);
            uint2 pk = make_uint2(*(u32*)&h0, *(u32*)&h1);
            *(uint2*)&((f16*)outp)[(size_t)r * D + 4 * li] = pk;
        }
    }
}

extern "C" void kernel_launch(void* const* d_in, const int* in_sizes, int n_in,
                              void* d_out, int out_size, void* d_ws, size_t ws_size,
                              hipStream_t stream) {
    const float* x   = (const float*)d_in[0];
    const int*   edg = (const int*)d_in[1];
    const float* W1  = (const float*)d_in[2];
    const float* W2  = (const float*)d_in[3];
    const float* as1 = (const float*)d_in[4];
    const float* ad1 = (const float*)d_in[5];
    const float* as2 = (const float*)d_in[6];
    const float* ad2 = (const float*)d_in[7];

    const int N = in_sizes[0] / 256;
    const int E = in_sizes[1] / 2;
    const int* row = edg;
    const int* col = edg + E;
    const int NB = (N + 511) / 512;

    // Workspace layout
    char* p = (char*)d_ws;
    f16* h1f = (f16*)p;     p += (size_t)N * 128 * 2;   // layer-1 features, fp16
    f16* h2f = (f16*)p;     p += (size_t)N * 64 * 2;    // layer-2 features, fp16
    // staging (dead before g1 written) aliases g1 (fp16)
    char* g1s = p;
    f16* g1h = (f16*)g1s;
    uint2* staging = (uint2*)g1s;
    size_t g1_bytes = (size_t)N * 128 * 2;
    size_t stg_bytes = (size_t)NB * BKT_CAP * 8;
    p += (g1_bytes > stg_bytes) ? g1_bytes : stg_bytes;
    float* sm = (float*)p;  p += (size_t)N * 4 * 4;     // s1,d1,s2,d2
    float* s1 = sm + (size_t)N * 0;
    float* d1 = sm + (size_t)N * 1;
    float* s2 = sm + (size_t)N * 2;
    float* d2 = sm + (size_t)N * 3;
    f16* B1 = (f16*)p;      p += (size_t)128 * 256 * 2; // W1 fragment-order fp16
    f16* B2 = (f16*)p;      p += (size_t)64 * 128 * 2;  // W2 fragment-order fp16
    int* gcnt = (int*)p;    p += 256 * 4;               // bucket counts (zeroed)
    int* rp  = (int*)p;     p += (size_t)(N + 1) * 4;   // CSR row_ptr
    int* cs  = (int*)p;     p += (size_t)E * 4;         // CSR col indices

    hipMemsetAsync(gcnt, 0, 256 * 4, stream);

    build_bswz_both<<<160, 256, 0, stream>>>(W1, B1, W2, B2);

    const int GB = (N + 63) / 64;

    // CSR build: bin -> per-bucket (gcnt scan + rp build + scatter)
    bin_kernel<<<(E + 4095) / 4096, 256, 0, stream>>>(row, col, gcnt, staging, E, NB);
    csr_scatter2<<<NB, 256, 0, stream>>>(staging, gcnt, rp, cs, N);

    // Layer 1
    gemm_mfma<256, 128, false, false><<<GB, 256, 0, stream>>>(x, B1, as1, ad1, h1f, s1, d1, N);
    gat_csr_f16<128, false><<<(N + 3) / 4, 256, 0, stream>>>(rp, cs, s1, d1, (const u32*)h1f,
                                                             g1h, N);

    // Layer 2 (fp16 g1 in, ELU fused into MFMA A-staging)
    gemm_mfma<128, 64, true, true><<<GB, 256, 0, stream>>>(g1h, B2, as2, ad2, h2f, s2, d2, N);
    gat_csr_f16<64, true><<<(N + 3) / 4, 256, 0, stream>>>(rp, cs, s2, d2, (const u32*)h2f,
                                                           d_out, N);
}